// Round 1
// baseline (1337.961 us; speedup 1.0000x reference)
//
#include <hip/hip_runtime.h>

#define NPTS  32768
#define KNB   16
#define CINC  256
#define PEC   32
#define HWN   16
#define CMID  288
#define L1OUT 1024
#define COUTC 512
#define EPSLN 1e-5f

__device__ __forceinline__ float leaky(float x) { return x > 0.f ? x : 0.1f * x; }

__device__ __forceinline__ float bf2f(unsigned short u) {
    union { unsigned int i; float f; } x; x.i = ((unsigned int)u) << 16; return x.f;
}
__device__ __forceinline__ unsigned short f2bf(float f) {
    unsigned int x = __float_as_uint(f);
    x = (x + 0x7fffu + ((x >> 16) & 1u)) >> 16;
    return (unsigned short)x;
}

// ---------------------------------------------------------------------------
// Kernel 1: per-point edge MLPs + gather aggregation + LN(288) -> xln [N,288]
// One 256-thread block per point.
// ---------------------------------------------------------------------------
__global__ __launch_bounds__(256) void edge_kernel(
    const float* __restrict__ xyz, const float* __restrict__ feats,
    const int* __restrict__ nei,
    const float* __restrict__ pe_w1, const float* __restrict__ pe_b1,
    const float* __restrict__ pe_g1, const float* __restrict__ pe_be1,
    const float* __restrict__ pe_w2, const float* __restrict__ pe_b2,
    const float* __restrict__ pe_g2, const float* __restrict__ pe_be2,
    const float* __restrict__ wn_w1, const float* __restrict__ wn_b1,
    const float* __restrict__ wn_g1, const float* __restrict__ wn_be1,
    const float* __restrict__ wn_w2, const float* __restrict__ wn_b2,
    const float* __restrict__ wn_g2, const float* __restrict__ wn_be2,
    const float* __restrict__ wn_w3, const float* __restrict__ wn_b3,
    const float* __restrict__ wn_g3, const float* __restrict__ wn_be3,
    const float* __restrict__ nm_g, const float* __restrict__ nm_b,
    float* __restrict__ xln)
{
    const int m = blockIdx.x;
    const int t = threadIdx.x;

    __shared__ int   nidx[KNB];
    __shared__ float loc[KNB][3];
    __shared__ float hpe[KNB][PEC];
    __shared__ float fpe[KNB][PEC];
    __shared__ float wh1[KNB][HWN];
    __shared__ float wh2[KNB][HWN];
    __shared__ float w3s[KNB][CINC];
    __shared__ float rs[4], rq[4], redm[2];

    if (t < KNB) nidx[t] = nei[m * KNB + t];
    __syncthreads();
    if (t < KNB * 3) {
        int k = t / 3, d = t % 3;
        loc[k][d] = xyz[nidx[k] * 3 + d] - xyz[m * 3 + d];
    }
    __syncthreads();

    // ---- PE layer 1: [K,3] @ [3,32] -> LN(32) -> leaky ----
    #pragma unroll
    for (int e = 0; e < 2; ++e) {
        int idx = t + 256 * e;
        int k = idx >> 5, c = idx & 31;
        float v = pe_b1[c] + loc[k][0] * pe_w1[c] + loc[k][1] * pe_w1[PEC + c]
                + loc[k][2] * pe_w1[2 * PEC + c];
        float s = v, q = v * v;
        #pragma unroll
        for (int off = 16; off; off >>= 1) { s += __shfl_down(s, off, 32); q += __shfl_down(q, off, 32); }
        s = __shfl(s, 0, 32); q = __shfl(q, 0, 32);
        float mu = s * (1.f / 32.f);
        float rstd = rsqrtf(q * (1.f / 32.f) - mu * mu + EPSLN);
        hpe[k][c] = leaky((v - mu) * rstd * pe_g1[c] + pe_be1[c]);
    }
    __syncthreads();

    // ---- PE layer 2: [K,32] @ [32,32] -> LN(32) (no leaky) ----
    #pragma unroll
    for (int e = 0; e < 2; ++e) {
        int idx = t + 256 * e;
        int k = idx >> 5, c = idx & 31;
        float v = pe_b2[c];
        #pragma unroll 8
        for (int j = 0; j < PEC; ++j) v += hpe[k][j] * pe_w2[j * PEC + c];
        float s = v, q = v * v;
        #pragma unroll
        for (int off = 16; off; off >>= 1) { s += __shfl_down(s, off, 32); q += __shfl_down(q, off, 32); }
        s = __shfl(s, 0, 32); q = __shfl(q, 0, 32);
        float mu = s * (1.f / 32.f);
        float rstd = rsqrtf(q * (1.f / 32.f) - mu * mu + EPSLN);
        fpe[k][c] = (v - mu) * rstd * pe_g2[c] + pe_be2[c];
    }

    // ---- WN layer 1: [K,3] @ [3,16] -> LN(16) -> leaky ----
    {
        int k = t >> 4, c = t & 15;
        float v = wn_b1[c] + loc[k][0] * wn_w1[c] + loc[k][1] * wn_w1[HWN + c]
                + loc[k][2] * wn_w1[2 * HWN + c];
        float s = v, q = v * v;
        #pragma unroll
        for (int off = 8; off; off >>= 1) { s += __shfl_down(s, off, 16); q += __shfl_down(q, off, 16); }
        s = __shfl(s, 0, 16); q = __shfl(q, 0, 16);
        float mu = s * (1.f / 16.f);
        float rstd = rsqrtf(q * (1.f / 16.f) - mu * mu + EPSLN);
        wh1[k][c] = leaky((v - mu) * rstd * wn_g1[c] + wn_be1[c]);
    }
    __syncthreads();

    // ---- WN layer 2: [K,16] @ [16,16] -> LN(16) -> leaky ----
    {
        int k = t >> 4, c = t & 15;
        float v = wn_b2[c];
        #pragma unroll
        for (int j = 0; j < HWN; ++j) v += wh1[k][j] * wn_w2[j * HWN + c];
        float s = v, q = v * v;
        #pragma unroll
        for (int off = 8; off; off >>= 1) { s += __shfl_down(s, off, 16); q += __shfl_down(q, off, 16); }
        s = __shfl(s, 0, 16); q = __shfl(q, 0, 16);
        float mu = s * (1.f / 16.f);
        float rstd = rsqrtf(q * (1.f / 16.f) - mu * mu + EPSLN);
        wh2[k][c] = leaky((v - mu) * rstd * wn_g2[c] + wn_be2[c]);
    }
    __syncthreads();

    // ---- WN layer 3: [K,16] @ [16,256] -> LN(256) (no leaky) ----
    {
        int k = t >> 4, j = t & 15;
        float vv[16];
        float s = 0.f, q = 0.f;
        #pragma unroll
        for (int i = 0; i < 16; ++i) {
            int c = j + 16 * i;
            float v = wn_b3[c];
            #pragma unroll
            for (int h = 0; h < HWN; ++h) v += wh2[k][h] * wn_w3[h * CINC + c];
            vv[i] = v; s += v; q += v * v;
        }
        #pragma unroll
        for (int off = 8; off; off >>= 1) { s += __shfl_down(s, off, 16); q += __shfl_down(q, off, 16); }
        s = __shfl(s, 0, 16); q = __shfl(q, 0, 16);
        float mu = s * (1.f / 256.f);
        float rstd = rsqrtf(q * (1.f / 256.f) - mu * mu + EPSLN);
        #pragma unroll
        for (int i = 0; i < 16; ++i) {
            int c = j + 16 * i;
            w3s[k][c] = (vv[i] - mu) * rstd * wn_g3[c] + wn_be3[c];
        }
    }
    __syncthreads();

    // ---- aggregation: agg[c] = sum_k feats[nidx[k]][c] * w[k][c]; pe sums ----
    float aggv = 0.f;
    {
        int c = t;
        #pragma unroll
        for (int k = 0; k < KNB; ++k)
            aggv += feats[(size_t)nidx[k] * CINC + c] * w3s[k][c];
    }
    float pev = 0.f;
    if (t < PEC) {
        #pragma unroll
        for (int k = 0; k < KNB; ++k) pev += fpe[k][t];
    }

    // ---- LN over 288 of concat([agg, pe]) -> xln ----
    float s = aggv, q = aggv * aggv;
    if (t < PEC) { s += pev; q += pev * pev; }
    #pragma unroll
    for (int off = 32; off; off >>= 1) { s += __shfl_down(s, off); q += __shfl_down(q, off); }
    if ((t & 63) == 0) { rs[t >> 6] = s; rq[t >> 6] = q; }
    __syncthreads();
    if (t == 0) {
        redm[0] = rs[0] + rs[1] + rs[2] + rs[3];
        redm[1] = rq[0] + rq[1] + rq[2] + rq[3];
    }
    __syncthreads();
    float mu = redm[0] * (1.f / 288.f);
    float rstd = rsqrtf(redm[1] * (1.f / 288.f) - mu * mu + EPSLN);
    xln[(size_t)m * CMID + t] = (aggv - mu) * rstd * nm_g[t] + nm_b[t];
    if (t < PEC)
        xln[(size_t)m * CMID + 256 + t] = (pev - mu) * rstd * nm_g[256 + t] + nm_b[256 + t];
}

// ---------------------------------------------------------------------------
// Kernel 2: h1 = leaky(xln @ l1_w + l1_b), stored bf16. Tiled 64x64, BK=16.
// ---------------------------------------------------------------------------
__global__ __launch_bounds__(256) void gemm1_kernel(
    const float* __restrict__ A, const float* __restrict__ Bw,
    const float* __restrict__ bias, unsigned short* __restrict__ C)
{
    __shared__ float As[16][68];   // [k][m], padded for alignment/conflicts
    __shared__ float Bs[16][64];   // [k][n]
    const int t = threadIdx.x;
    const int tx = t & 15, ty = t >> 4;
    const int m0 = blockIdx.y * 64;
    const int n0 = blockIdx.x * 64;
    const int ar = t >> 2, ac = (t & 3) * 4;
    const int br = t >> 4, bc = (t & 15) * 4;

    float acc[4][4] = {};
    for (int kt = 0; kt < CMID; kt += 16) {
        float4 av = *(const float4*)(A + (size_t)(m0 + ar) * CMID + kt + ac);
        float4 bv = *(const float4*)(Bw + (size_t)(kt + br) * L1OUT + n0 + bc);
        As[ac + 0][ar] = av.x; As[ac + 1][ar] = av.y;
        As[ac + 2][ar] = av.z; As[ac + 3][ar] = av.w;
        *(float4*)&Bs[br][bc] = bv;
        __syncthreads();
        #pragma unroll
        for (int kk = 0; kk < 16; ++kk) {
            float4 a = *(const float4*)&As[kk][ty * 4];
            float4 b = *(const float4*)&Bs[kk][tx * 4];
            float aa[4] = {a.x, a.y, a.z, a.w};
            float bb[4] = {b.x, b.y, b.z, b.w};
            #pragma unroll
            for (int i = 0; i < 4; ++i)
                #pragma unroll
                for (int j = 0; j < 4; ++j) acc[i][j] += aa[i] * bb[j];
        }
        __syncthreads();
    }
    #pragma unroll
    for (int i = 0; i < 4; ++i) {
        int mm = m0 + ty * 4 + i;
        int nn = n0 + tx * 4;
        ushort4 o;
        o.x = f2bf(leaky(acc[i][0] + bias[nn + 0]));
        o.y = f2bf(leaky(acc[i][1] + bias[nn + 1]));
        o.z = f2bf(leaky(acc[i][2] + bias[nn + 2]));
        o.w = f2bf(leaky(acc[i][3] + bias[nn + 3]));
        *(ushort4*)(C + (size_t)mm * L1OUT + nn) = o;
    }
}

// ---------------------------------------------------------------------------
// Kernel 3: out = leaky(h1 @ l2_w + l2_b + feats @ sc_w + sc_b). Dual-K GEMM.
// ---------------------------------------------------------------------------
__global__ __launch_bounds__(256) void gemm2_kernel(
    const unsigned short* __restrict__ H, const float* __restrict__ F,
    const float* __restrict__ W2, const float* __restrict__ Wsc,
    const float* __restrict__ b2, const float* __restrict__ bsc,
    float* __restrict__ Out)
{
    __shared__ float As[16][68];
    __shared__ float Bs[16][64];
    const int t = threadIdx.x;
    const int tx = t & 15, ty = t >> 4;
    const int m0 = blockIdx.y * 64;
    const int n0 = blockIdx.x * 64;
    const int ar = t >> 2, ac = (t & 3) * 4;
    const int br = t >> 4, bc = (t & 15) * 4;

    float acc[4][4] = {};
    // phase 1: K = 1024 over bf16 h1 / l2_w
    for (int kt = 0; kt < L1OUT; kt += 16) {
        ushort4 hu = *(const ushort4*)(H + (size_t)(m0 + ar) * L1OUT + kt + ac);
        float4 bv = *(const float4*)(W2 + (size_t)(kt + br) * COUTC + n0 + bc);
        As[ac + 0][ar] = bf2f(hu.x); As[ac + 1][ar] = bf2f(hu.y);
        As[ac + 2][ar] = bf2f(hu.z); As[ac + 3][ar] = bf2f(hu.w);
        *(float4*)&Bs[br][bc] = bv;
        __syncthreads();
        #pragma unroll
        for (int kk = 0; kk < 16; ++kk) {
            float4 a = *(const float4*)&As[kk][ty * 4];
            float4 b = *(const float4*)&Bs[kk][tx * 4];
            float aa[4] = {a.x, a.y, a.z, a.w};
            float bb[4] = {b.x, b.y, b.z, b.w};
            #pragma unroll
            for (int i = 0; i < 4; ++i)
                #pragma unroll
                for (int j = 0; j < 4; ++j) acc[i][j] += aa[i] * bb[j];
        }
        __syncthreads();
    }
    // phase 2: K = 256 over fp32 feats / sc_w (fused shortcut)
    for (int kt = 0; kt < CINC; kt += 16) {
        float4 av = *(const float4*)(F + (size_t)(m0 + ar) * CINC + kt + ac);
        float4 bv = *(const float4*)(Wsc + (size_t)(kt + br) * COUTC + n0 + bc);
        As[ac + 0][ar] = av.x; As[ac + 1][ar] = av.y;
        As[ac + 2][ar] = av.z; As[ac + 3][ar] = av.w;
        *(float4*)&Bs[br][bc] = bv;
        __syncthreads();
        #pragma unroll
        for (int kk = 0; kk < 16; ++kk) {
            float4 a = *(const float4*)&As[kk][ty * 4];
            float4 b = *(const float4*)&Bs[kk][tx * 4];
            float aa[4] = {a.x, a.y, a.z, a.w};
            float bb[4] = {b.x, b.y, b.z, b.w};
            #pragma unroll
            for (int i = 0; i < 4; ++i)
                #pragma unroll
                for (int j = 0; j < 4; ++j) acc[i][j] += aa[i] * bb[j];
        }
        __syncthreads();
    }
    #pragma unroll
    for (int i = 0; i < 4; ++i) {
        int mm = m0 + ty * 4 + i;
        int nn = n0 + tx * 4;
        float4 o;
        o.x = leaky(acc[i][0] + b2[nn + 0] + bsc[nn + 0]);
        o.y = leaky(acc[i][1] + b2[nn + 1] + bsc[nn + 1]);
        o.z = leaky(acc[i][2] + b2[nn + 2] + bsc[nn + 2]);
        o.w = leaky(acc[i][3] + b2[nn + 3] + bsc[nn + 3]);
        *(float4*)(Out + (size_t)mm * COUTC + nn) = o;
    }
}

extern "C" void kernel_launch(void* const* d_in, const int* in_sizes, int n_in,
                              void* d_out, int out_size, void* d_ws, size_t ws_size,
                              hipStream_t stream)
{
    const float* xyz    = (const float*)d_in[0];
    const float* feats  = (const float*)d_in[1];
    const int*   nei    = (const int*)d_in[2];
    const float* pe_w1  = (const float*)d_in[3];
    const float* pe_b1  = (const float*)d_in[4];
    const float* pe_g1  = (const float*)d_in[5];
    const float* pe_be1 = (const float*)d_in[6];
    const float* pe_w2  = (const float*)d_in[7];
    const float* pe_b2  = (const float*)d_in[8];
    const float* pe_g2  = (const float*)d_in[9];
    const float* pe_be2 = (const float*)d_in[10];
    const float* wn_w1  = (const float*)d_in[11];
    const float* wn_b1  = (const float*)d_in[12];
    const float* wn_g1  = (const float*)d_in[13];
    const float* wn_be1 = (const float*)d_in[14];
    const float* wn_w2  = (const float*)d_in[15];
    const float* wn_b2  = (const float*)d_in[16];
    const float* wn_g2  = (const float*)d_in[17];
    const float* wn_be2 = (const float*)d_in[18];
    const float* wn_w3  = (const float*)d_in[19];
    const float* wn_b3  = (const float*)d_in[20];
    const float* wn_g3  = (const float*)d_in[21];
    const float* wn_be3 = (const float*)d_in[22];
    const float* nm_g   = (const float*)d_in[23];
    const float* nm_b   = (const float*)d_in[24];
    const float* l1_w   = (const float*)d_in[25];
    const float* l1_b   = (const float*)d_in[26];
    const float* l2_w   = (const float*)d_in[27];
    const float* l2_b   = (const float*)d_in[28];
    const float* sc_w   = (const float*)d_in[29];
    const float* sc_b   = (const float*)d_in[30];

    float* xln = (float*)d_ws;                                      // 32768*288*4  = 37.75 MB
    unsigned short* h1 =
        (unsigned short*)((char*)d_ws + (size_t)NPTS * CMID * 4);   // 32768*1024*2 = 67.1 MB

    edge_kernel<<<NPTS, 256, 0, stream>>>(
        xyz, feats, nei,
        pe_w1, pe_b1, pe_g1, pe_be1, pe_w2, pe_b2, pe_g2, pe_be2,
        wn_w1, wn_b1, wn_g1, wn_be1, wn_w2, wn_b2, wn_g2, wn_be2,
        wn_w3, wn_b3, wn_g3, wn_be3, nm_g, nm_b, xln);

    gemm1_kernel<<<dim3(L1OUT / 64, NPTS / 64), 256, 0, stream>>>(xln, l1_w, l1_b, h1);

    gemm2_kernel<<<dim3(COUTC / 64, NPTS / 64), 256, 0, stream>>>(
        h1, feats, l2_w, sc_w, l2_b, sc_b, (float*)d_out);
}

// Round 2
// 703.189 us; speedup vs baseline: 1.9027x; 1.9027x over previous
//
#include <hip/hip_runtime.h>

#define NPTS  32768
#define KNB   16
#define CINC  256
#define PEC   32
#define HWN   16
#define CMID  288
#define L1OUT 1024
#define COUTC 512
#define EPSLN 1e-5f

typedef __attribute__((ext_vector_type(8))) short short8;
typedef __attribute__((ext_vector_type(4))) float f32x4;

__device__ __forceinline__ float leaky(float x) { return x > 0.f ? x : 0.1f * x; }

__device__ __forceinline__ float bf2f(unsigned short u) {
    union { unsigned int i; float f; } x; x.i = ((unsigned int)u) << 16; return x.f;
}
__device__ __forceinline__ unsigned short f2bf(float f) {
    unsigned int x = __float_as_uint(f);
    x = (x + 0x7fffu + ((x >> 16) & 1u)) >> 16;
    return (unsigned short)x;
}

// async global->LDS, 16B per lane, dest = wave-uniform base + lane*16
__device__ __forceinline__ void gld_lds16(const unsigned short* g, unsigned short* l) {
    __builtin_amdgcn_global_load_lds(
        (const __attribute__((address_space(1))) unsigned int*)g,
        (__attribute__((address_space(3))) unsigned int*)l,
        16, 0, 0);
}

// Stage a 128x32 bf16 tile (8 KB) from row-major global [ld elems] into LDS.
// LDS physical [row][kp] holds logical k = kp ^ ((row&3)*8)  (XOR swizzle so
// ds_read_b128 fragment reads spread across banks; staging stays lane-linear
// as global_load_lds requires).
__device__ __forceinline__ void stage_tile(const unsigned short* __restrict__ g,
                                           size_t ld, int row0, int k0,
                                           unsigned short* lds, int wave, int lane)
{
    #pragma unroll
    for (int r = 0; r < 2; ++r) {
        int e   = r * 2048 + wave * 512 + lane * 8;  // linear LDS element
        int row = e >> 5;
        int kp  = e & 31;
        int kl  = kp ^ ((row & 3) << 3);
        const unsigned short* src = g + (size_t)(row0 + row) * ld + (k0 + kl);
        gld_lds16(src, lds + r * 2048 + wave * 512);
    }
}

// ---------------------------------------------------------------------------
// Kernel 1: per-point edge MLPs + gather aggregation + LN(288) -> xln bf16
// ---------------------------------------------------------------------------
__global__ __launch_bounds__(256) void edge_kernel(
    const float* __restrict__ xyz, const float* __restrict__ feats,
    const int* __restrict__ nei,
    const float* __restrict__ pe_w1, const float* __restrict__ pe_b1,
    const float* __restrict__ pe_g1, const float* __restrict__ pe_be1,
    const float* __restrict__ pe_w2, const float* __restrict__ pe_b2,
    const float* __restrict__ pe_g2, const float* __restrict__ pe_be2,
    const float* __restrict__ wn_w1, const float* __restrict__ wn_b1,
    const float* __restrict__ wn_g1, const float* __restrict__ wn_be1,
    const float* __restrict__ wn_w2, const float* __restrict__ wn_b2,
    const float* __restrict__ wn_g2, const float* __restrict__ wn_be2,
    const float* __restrict__ wn_w3, const float* __restrict__ wn_b3,
    const float* __restrict__ wn_g3, const float* __restrict__ wn_be3,
    const float* __restrict__ nm_g, const float* __restrict__ nm_b,
    unsigned short* __restrict__ xln)
{
    const int m = blockIdx.x;
    const int t = threadIdx.x;

    __shared__ int   nidx[KNB];
    __shared__ float loc[KNB][3];
    __shared__ float hpe[KNB][PEC];
    __shared__ float fpe[KNB][PEC];
    __shared__ float wh1[KNB][HWN];
    __shared__ float wh2[KNB][HWN];
    __shared__ float w3s[KNB][CINC];
    __shared__ float rs[4], rq[4], redm[2];

    if (t < KNB) nidx[t] = nei[m * KNB + t];
    __syncthreads();
    if (t < KNB * 3) {
        int k = t / 3, d = t % 3;
        loc[k][d] = xyz[nidx[k] * 3 + d] - xyz[m * 3 + d];
    }
    __syncthreads();

    // ---- PE layer 1 ----
    #pragma unroll
    for (int e = 0; e < 2; ++e) {
        int idx = t + 256 * e;
        int k = idx >> 5, c = idx & 31;
        float v = pe_b1[c] + loc[k][0] * pe_w1[c] + loc[k][1] * pe_w1[PEC + c]
                + loc[k][2] * pe_w1[2 * PEC + c];
        float s = v, q = v * v;
        #pragma unroll
        for (int off = 16; off; off >>= 1) { s += __shfl_down(s, off, 32); q += __shfl_down(q, off, 32); }
        s = __shfl(s, 0, 32); q = __shfl(q, 0, 32);
        float mu = s * (1.f / 32.f);
        float rstd = rsqrtf(q * (1.f / 32.f) - mu * mu + EPSLN);
        hpe[k][c] = leaky((v - mu) * rstd * pe_g1[c] + pe_be1[c]);
    }
    __syncthreads();

    // ---- PE layer 2 ----
    #pragma unroll
    for (int e = 0; e < 2; ++e) {
        int idx = t + 256 * e;
        int k = idx >> 5, c = idx & 31;
        float v = pe_b2[c];
        #pragma unroll 8
        for (int j = 0; j < PEC; ++j) v += hpe[k][j] * pe_w2[j * PEC + c];
        float s = v, q = v * v;
        #pragma unroll
        for (int off = 16; off; off >>= 1) { s += __shfl_down(s, off, 32); q += __shfl_down(q, off, 32); }
        s = __shfl(s, 0, 32); q = __shfl(q, 0, 32);
        float mu = s * (1.f / 32.f);
        float rstd = rsqrtf(q * (1.f / 32.f) - mu * mu + EPSLN);
        fpe[k][c] = (v - mu) * rstd * pe_g2[c] + pe_be2[c];
    }

    // ---- WN layer 1 ----
    {
        int k = t >> 4, c = t & 15;
        float v = wn_b1[c] + loc[k][0] * wn_w1[c] + loc[k][1] * wn_w1[HWN + c]
                + loc[k][2] * wn_w1[2 * HWN + c];
        float s = v, q = v * v;
        #pragma unroll
        for (int off = 8; off; off >>= 1) { s += __shfl_down(s, off, 16); q += __shfl_down(q, off, 16); }
        s = __shfl(s, 0, 16); q = __shfl(q, 0, 16);
        float mu = s * (1.f / 16.f);
        float rstd = rsqrtf(q * (1.f / 16.f) - mu * mu + EPSLN);
        wh1[k][c] = leaky((v - mu) * rstd * wn_g1[c] + wn_be1[c]);
    }
    __syncthreads();

    // ---- WN layer 2 ----
    {
        int k = t >> 4, c = t & 15;
        float v = wn_b2[c];
        #pragma unroll
        for (int j = 0; j < HWN; ++j) v += wh1[k][j] * wn_w2[j * HWN + c];
        float s = v, q = v * v;
        #pragma unroll
        for (int off = 8; off; off >>= 1) { s += __shfl_down(s, off, 16); q += __shfl_down(q, off, 16); }
        s = __shfl(s, 0, 16); q = __shfl(q, 0, 16);
        float mu = s * (1.f / 16.f);
        float rstd = rsqrtf(q * (1.f / 16.f) - mu * mu + EPSLN);
        wh2[k][c] = leaky((v - mu) * rstd * wn_g2[c] + wn_be2[c]);
    }
    __syncthreads();

    // ---- WN layer 3 ----
    {
        int k = t >> 4, j = t & 15;
        float vv[16];
        float s = 0.f, q = 0.f;
        #pragma unroll
        for (int i = 0; i < 16; ++i) {
            int c = j + 16 * i;
            float v = wn_b3[c];
            #pragma unroll
            for (int h = 0; h < HWN; ++h) v += wh2[k][h] * wn_w3[h * CINC + c];
            vv[i] = v; s += v; q += v * v;
        }
        #pragma unroll
        for (int off = 8; off; off >>= 1) { s += __shfl_down(s, off, 16); q += __shfl_down(q, off, 16); }
        s = __shfl(s, 0, 16); q = __shfl(q, 0, 16);
        float mu = s * (1.f / 256.f);
        float rstd = rsqrtf(q * (1.f / 256.f) - mu * mu + EPSLN);
        #pragma unroll
        for (int i = 0; i < 16; ++i) {
            int c = j + 16 * i;
            w3s[k][c] = (vv[i] - mu) * rstd * wn_g3[c] + wn_be3[c];
        }
    }
    __syncthreads();

    // ---- aggregation ----
    float aggv = 0.f;
    {
        int c = t;
        #pragma unroll
        for (int k = 0; k < KNB; ++k)
            aggv += feats[(size_t)nidx[k] * CINC + c] * w3s[k][c];
    }
    float pev = 0.f;
    if (t < PEC) {
        #pragma unroll
        for (int k = 0; k < KNB; ++k) pev += fpe[k][t];
    }

    // ---- LN(288) -> bf16 xln ----
    float s = aggv, q = aggv * aggv;
    if (t < PEC) { s += pev; q += pev * pev; }
    #pragma unroll
    for (int off = 32; off; off >>= 1) { s += __shfl_down(s, off); q += __shfl_down(q, off); }
    if ((t & 63) == 0) { rs[t >> 6] = s; rq[t >> 6] = q; }
    __syncthreads();
    if (t == 0) {
        redm[0] = rs[0] + rs[1] + rs[2] + rs[3];
        redm[1] = rq[0] + rq[1] + rq[2] + rq[3];
    }
    __syncthreads();
    float mu = redm[0] * (1.f / 288.f);
    float rstd = rsqrtf(redm[1] * (1.f / 288.f) - mu * mu + EPSLN);
    xln[(size_t)m * CMID + t] = f2bf((aggv - mu) * rstd * nm_g[t] + nm_b[t]);
    if (t < PEC)
        xln[(size_t)m * CMID + 256 + t] = f2bf((pev - mu) * rstd * nm_g[256 + t] + nm_b[256 + t]);
}

// ---------------------------------------------------------------------------
// Conversion kernels: fp32 [K][N] -> bf16 [N][K] transpose, and flat bf16 cast
// ---------------------------------------------------------------------------
__global__ __launch_bounds__(256) void transpose_bf16_kernel(
    const float* __restrict__ src, unsigned short* __restrict__ dst, int K, int N)
{
    __shared__ float tile[32][33];
    const int k0 = blockIdx.y * 32, n0 = blockIdx.x * 32;
    const int tx = threadIdx.x & 31, ty = threadIdx.x >> 5;  // ty in [0,8)
    #pragma unroll
    for (int i = ty; i < 32; i += 8)
        tile[i][tx] = src[(size_t)(k0 + i) * N + n0 + tx];
    __syncthreads();
    #pragma unroll
    for (int i = ty; i < 32; i += 8)
        dst[(size_t)(n0 + i) * K + k0 + tx] = f2bf(tile[tx][i]);
}

__global__ __launch_bounds__(256) void feats_bf16_kernel(
    const float* __restrict__ src, unsigned short* __restrict__ dst)
{
    int i = (blockIdx.x * 256 + threadIdx.x) * 4;
    float4 v = *(const float4*)(src + i);
    ushort4 o;
    o.x = f2bf(v.x); o.y = f2bf(v.y); o.z = f2bf(v.z); o.w = f2bf(v.w);
    *(ushort4*)(dst + i) = o;
}

// ---------------------------------------------------------------------------
// Kernel 2: h1 = leaky(xln @ l1_w + l1_b), bf16 MFMA, 128x128 tile, BK=32
// ---------------------------------------------------------------------------
__global__ __launch_bounds__(256) void gemm1_mfma(
    const unsigned short* __restrict__ A,   // [NPTS][288] bf16
    const unsigned short* __restrict__ BT,  // [1024][288] bf16 (l1_w^T)
    const float* __restrict__ bias,
    unsigned short* __restrict__ C)         // [NPTS][1024] bf16
{
    __shared__ unsigned short As[128 * 32];
    __shared__ unsigned short Bs[128 * 32];
    const int t = threadIdx.x;
    const int lane = t & 63, wave = t >> 6;
    const int wm = wave >> 1, wn = wave & 1;
    const int m0 = blockIdx.y * 128, n0 = blockIdx.x * 128;
    const int l15 = lane & 15, j0 = (lane >> 4) << 3;

    f32x4 zero = {0.f, 0.f, 0.f, 0.f};
    f32x4 acc[4][4];
    #pragma unroll
    for (int i = 0; i < 4; ++i)
        #pragma unroll
        for (int j = 0; j < 4; ++j) acc[i][j] = zero;

    for (int kt = 0; kt < CMID; kt += 32) {
        stage_tile(A,  CMID, m0, kt, As, wave, lane);
        stage_tile(BT, CMID, n0, kt, Bs, wave, lane);
        __syncthreads();
        short8 af[4], bf[4];
        #pragma unroll
        for (int i = 0; i < 4; ++i) {
            int ar = wm * 64 + i * 16 + l15;
            af[i] = *(const short8*)&As[ar * 32 + (j0 ^ ((ar & 3) << 3))];
            int br = wn * 64 + i * 16 + l15;
            bf[i] = *(const short8*)&Bs[br * 32 + (j0 ^ ((br & 3) << 3))];
        }
        #pragma unroll
        for (int i = 0; i < 4; ++i)
            #pragma unroll
            for (int j = 0; j < 4; ++j)
                acc[i][j] = __builtin_amdgcn_mfma_f32_16x16x32_bf16(af[i], bf[j], acc[i][j], 0, 0, 0);
        __syncthreads();
    }

    const int q = lane >> 4;
    #pragma unroll
    for (int j = 0; j < 4; ++j) {
        int ncol = n0 + wn * 64 + j * 16 + l15;
        float bv = bias[ncol];
        #pragma unroll
        for (int i = 0; i < 4; ++i) {
            int mbase = m0 + wm * 64 + i * 16 + q * 4;
            #pragma unroll
            for (int r = 0; r < 4; ++r)
                C[(size_t)(mbase + r) * L1OUT + ncol] = f2bf(leaky(acc[i][j][r] + bv));
        }
    }
}

// ---------------------------------------------------------------------------
// Kernel 3: out = leaky(h1 @ l2_w + feats @ sc_w + b2 + bsc), dual-K bf16 MFMA
// ---------------------------------------------------------------------------
__global__ __launch_bounds__(256) void gemm2_mfma(
    const unsigned short* __restrict__ H,    // [NPTS][1024] bf16
    const unsigned short* __restrict__ W2T,  // [512][1024] bf16
    const unsigned short* __restrict__ F,    // [NPTS][256] bf16
    const unsigned short* __restrict__ WscT, // [512][256] bf16
    const float* __restrict__ b2, const float* __restrict__ bsc,
    float* __restrict__ Out)                 // [NPTS][512] fp32
{
    __shared__ unsigned short As[128 * 32];
    __shared__ unsigned short Bs[128 * 32];
    const int t = threadIdx.x;
    const int lane = t & 63, wave = t >> 6;
    const int wm = wave >> 1, wn = wave & 1;
    const int m0 = blockIdx.y * 128, n0 = blockIdx.x * 128;
    const int l15 = lane & 15, j0 = (lane >> 4) << 3;

    f32x4 zero = {0.f, 0.f, 0.f, 0.f};
    f32x4 acc[4][4];
    #pragma unroll
    for (int i = 0; i < 4; ++i)
        #pragma unroll
        for (int j = 0; j < 4; ++j) acc[i][j] = zero;

    // phase 1: K = 1024
    for (int kt = 0; kt < L1OUT; kt += 32) {
        stage_tile(H,   L1OUT, m0, kt, As, wave, lane);
        stage_tile(W2T, L1OUT, n0, kt, Bs, wave, lane);
        __syncthreads();
        short8 af[4], bf[4];
        #pragma unroll
        for (int i = 0; i < 4; ++i) {
            int ar = wm * 64 + i * 16 + l15;
            af[i] = *(const short8*)&As[ar * 32 + (j0 ^ ((ar & 3) << 3))];
            int br = wn * 64 + i * 16 + l15;
            bf[i] = *(const short8*)&Bs[br * 32 + (j0 ^ ((br & 3) << 3))];
        }
        #pragma unroll
        for (int i = 0; i < 4; ++i)
            #pragma unroll
            for (int j = 0; j < 4; ++j)
                acc[i][j] = __builtin_amdgcn_mfma_f32_16x16x32_bf16(af[i], bf[j], acc[i][j], 0, 0, 0);
        __syncthreads();
    }
    // phase 2: K = 256 (fused shortcut)
    for (int kt = 0; kt < CINC; kt += 32) {
        stage_tile(F,    CINC, m0, kt, As, wave, lane);
        stage_tile(WscT, CINC, n0, kt, Bs, wave, lane);
        __syncthreads();
        short8 af[4], bf[4];
        #pragma unroll
        for (int i = 0; i < 4; ++i) {
            int ar = wm * 64 + i * 16 + l15;
            af[i] = *(const short8*)&As[ar * 32 + (j0 ^ ((ar & 3) << 3))];
            int br = wn * 64 + i * 16 + l15;
            bf[i] = *(const short8*)&Bs[br * 32 + (j0 ^ ((br & 3) << 3))];
        }
        #pragma unroll
        for (int i = 0; i < 4; ++i)
            #pragma unroll
            for (int j = 0; j < 4; ++j)
                acc[i][j] = __builtin_amdgcn_mfma_f32_16x16x32_bf16(af[i], bf[j], acc[i][j], 0, 0, 0);
        __syncthreads();
    }

    const int q = lane >> 4;
    #pragma unroll
    for (int j = 0; j < 4; ++j) {
        int ncol = n0 + wn * 64 + j * 16 + l15;
        float bv = b2[ncol] + bsc[ncol];
        #pragma unroll
        for (int i = 0; i < 4; ++i) {
            int mbase = m0 + wm * 64 + i * 16 + q * 4;
            #pragma unroll
            for (int r = 0; r < 4; ++r)
                Out[(size_t)(mbase + r) * COUTC + ncol] = leaky(acc[i][j][r] + bv);
        }
    }
}

extern "C" void kernel_launch(void* const* d_in, const int* in_sizes, int n_in,
                              void* d_out, int out_size, void* d_ws, size_t ws_size,
                              hipStream_t stream)
{
    const float* xyz    = (const float*)d_in[0];
    const float* feats  = (const float*)d_in[1];
    const int*   nei    = (const int*)d_in[2];
    const float* pe_w1  = (const float*)d_in[3];
    const float* pe_b1  = (const float*)d_in[4];
    const float* pe_g1  = (const float*)d_in[5];
    const float* pe_be1 = (const float*)d_in[6];
    const float* pe_w2  = (const float*)d_in[7];
    const float* pe_b2  = (const float*)d_in[8];
    const float* pe_g2  = (const float*)d_in[9];
    const float* pe_be2 = (const float*)d_in[10];
    const float* wn_w1  = (const float*)d_in[11];
    const float* wn_b1  = (const float*)d_in[12];
    const float* wn_g1  = (const float*)d_in[13];
    const float* wn_be1 = (const float*)d_in[14];
    const float* wn_w2  = (const float*)d_in[15];
    const float* wn_b2  = (const float*)d_in[16];
    const float* wn_g2  = (const float*)d_in[17];
    const float* wn_be2 = (const float*)d_in[18];
    const float* wn_w3  = (const float*)d_in[19];
    const float* wn_b3  = (const float*)d_in[20];
    const float* wn_g3  = (const float*)d_in[21];
    const float* wn_be3 = (const float*)d_in[22];
    const float* nm_g   = (const float*)d_in[23];
    const float* nm_b   = (const float*)d_in[24];
    const float* l1_w   = (const float*)d_in[25];
    const float* l1_b   = (const float*)d_in[26];
    const float* l2_w   = (const float*)d_in[27];
    const float* l2_b   = (const float*)d_in[28];
    const float* sc_w   = (const float*)d_in[29];
    const float* sc_b   = (const float*)d_in[30];

    char* ws = (char*)d_ws;
    unsigned short* xln    = (unsigned short*)(ws);                         // 32768*288*2  = 18,874,368
    unsigned short* h1     = (unsigned short*)(ws + 18874368);              // 32768*1024*2 = 67,108,864
    unsigned short* featsb = (unsigned short*)(ws + 85983232);              // 32768*256*2  = 16,777,216
    unsigned short* l1_wT  = (unsigned short*)(ws + 102760448);             // 1024*288*2   = 589,824
    unsigned short* l2_wT  = (unsigned short*)(ws + 103350272);             // 512*1024*2   = 1,048,576
    unsigned short* sc_wT  = (unsigned short*)(ws + 104398848);             // 512*256*2    = 262,144

    // weight transposes + feats cast (small)
    transpose_bf16_kernel<<<dim3(L1OUT / 32, CMID / 32), 256, 0, stream>>>(l1_w, l1_wT, CMID, L1OUT);
    transpose_bf16_kernel<<<dim3(COUTC / 32, L1OUT / 32), 256, 0, stream>>>(l2_w, l2_wT, L1OUT, COUTC);
    transpose_bf16_kernel<<<dim3(COUTC / 32, CINC / 32), 256, 0, stream>>>(sc_w, sc_wT, CINC, COUTC);
    feats_bf16_kernel<<<(NPTS * CINC / 4) / 256, 256, 0, stream>>>(feats, featsb);

    edge_kernel<<<NPTS, 256, 0, stream>>>(
        xyz, feats, nei,
        pe_w1, pe_b1, pe_g1, pe_be1, pe_w2, pe_b2, pe_g2, pe_be2,
        wn_w1, wn_b1, wn_g1, wn_be1, wn_w2, wn_b2, wn_g2, wn_be2,
        wn_w3, wn_b3, wn_g3, wn_be3, nm_g, nm_b, xln);

    gemm1_mfma<<<dim3(L1OUT / 128, NPTS / 128), 256, 0, stream>>>(xln, l1_wT, l1_b, h1);

    gemm2_mfma<<<dim3(COUTC / 128, NPTS / 128), 256, 0, stream>>>(
        h1, l2_wT, featsb, sc_wT, l2_b, sc_b, (float*)d_out);
}

// Round 3
// 559.207 us; speedup vs baseline: 2.3926x; 1.2575x over previous
//
#include <hip/hip_runtime.h>

#define NPTS  32768
#define KNB   16
#define CINC  256
#define PEC   32
#define HWN   16
#define CMID  288
#define L1OUT 1024
#define COUTC 512
#define EPSLN 1e-5f

typedef __attribute__((ext_vector_type(8))) short short8;
typedef __attribute__((ext_vector_type(4))) float f32x4;

__device__ __forceinline__ float leaky(float x) { return x > 0.f ? x : 0.1f * x; }

__device__ __forceinline__ float bf2f(unsigned short u) {
    union { unsigned int i; float f; } x; x.i = ((unsigned int)u) << 16; return x.f;
}
__device__ __forceinline__ unsigned short f2bf(float f) {
    unsigned int x = __float_as_uint(f);
    x = (x + 0x7fffu + ((x >> 16) & 1u)) >> 16;
    return (unsigned short)x;
}

// async global->LDS, 16B per lane, dest = wave-uniform base + lane*16
__device__ __forceinline__ void gld_lds16(const unsigned short* g, unsigned short* l) {
    __builtin_amdgcn_global_load_lds(
        (const __attribute__((address_space(1))) unsigned int*)g,
        (__attribute__((address_space(3))) unsigned int*)l,
        16, 0, 0);
}

__device__ __forceinline__ void stage_tile(const unsigned short* __restrict__ g,
                                           size_t ld, int row0, int k0,
                                           unsigned short* lds, int wave, int lane)
{
    #pragma unroll
    for (int r = 0; r < 2; ++r) {
        int e   = r * 2048 + wave * 512 + lane * 8;
        int row = e >> 5;
        int kp  = e & 31;
        int kl  = kp ^ ((row & 3) << 3);
        const unsigned short* src = g + (size_t)(row0 + row) * ld + (k0 + kl);
        gld_lds16(src, lds + r * 2048 + wave * 512);
    }
}

// ---------------------------------------------------------------------------
// Stats kernel: G[h][h'] = mean_c W3[h][c]W3[h'][c]; wm3 = mean_c W3;
// gb = mean_c W3*b3; bm3 = mean b3; bsq = mean b3^2.
// st layout: G @0 (256), wm3 @256 (16), gb @272 (16), bm3 @288, bsq @289.
// ---------------------------------------------------------------------------
__global__ __launch_bounds__(256) void wn3_stats_kernel(
    const float* __restrict__ W3, const float* __restrict__ b3, float* __restrict__ st)
{
    int t = threadIdx.x;
    int h = t >> 4, hp = t & 15;
    float g = 0.f;
    for (int c = 0; c < CINC; ++c) g += W3[h * CINC + c] * W3[hp * CINC + c];
    st[t] = g * (1.f / CINC);
    if (t < 16) {
        float s = 0.f, sb = 0.f;
        for (int c = 0; c < CINC; ++c) { float w = W3[t * CINC + c]; s += w; sb += w * b3[c]; }
        st[256 + t] = s * (1.f / CINC);
        st[272 + t] = sb * (1.f / CINC);
    }
    if (t == 0) {
        float s = 0.f, q = 0.f;
        for (int c = 0; c < CINC; ++c) { float b = b3[c]; s += b; q += b * b; }
        st[288] = s * (1.f / CINC);
        st[289] = q * (1.f / CINC);
    }
}

// ---------------------------------------------------------------------------
// Phase A: one thread per edge. All LNs serial in-register, no LDS, no syncs.
// Outputs: fpe[e][32] bf16, Ut[point][18][16] fp32 (rows 0..15 = wh2[h][k],
// row 16 = r_k, row 17 = mu_k).
// ---------------------------------------------------------------------------
__global__ __launch_bounds__(256) void edge_mlp_kernel(
    const float* __restrict__ xyz, const int* __restrict__ nei,
    const float* __restrict__ pe_w1, const float* __restrict__ pe_b1,
    const float* __restrict__ pe_g1, const float* __restrict__ pe_be1,
    const float* __restrict__ pe_w2, const float* __restrict__ pe_b2,
    const float* __restrict__ pe_g2, const float* __restrict__ pe_be2,
    const float* __restrict__ wn_w1, const float* __restrict__ wn_b1,
    const float* __restrict__ wn_g1, const float* __restrict__ wn_be1,
    const float* __restrict__ wn_w2, const float* __restrict__ wn_b2,
    const float* __restrict__ wn_g2, const float* __restrict__ wn_be2,
    const float* __restrict__ st,
    unsigned short* __restrict__ fpe, float* __restrict__ Ut)
{
    const int e = blockIdx.x * 256 + threadIdx.x;
    const int m = e >> 4, k = e & 15;
    const int n = nei[e];
    const float lx = xyz[n * 3 + 0] - xyz[m * 3 + 0];
    const float ly = xyz[n * 3 + 1] - xyz[m * 3 + 1];
    const float lz = xyz[n * 3 + 2] - xyz[m * 3 + 2];

    // ---- PE layer 1: 3 -> 32, LN, leaky ----
    float h[32];
    float s = 0.f, q = 0.f;
    #pragma unroll
    for (int c = 0; c < 32; ++c) {
        float v = pe_b1[c] + lx * pe_w1[c] + ly * pe_w1[32 + c] + lz * pe_w1[64 + c];
        h[c] = v; s += v; q += v * v;
    }
    float mu = s * (1.f / 32.f);
    float rstd = rsqrtf(q * (1.f / 32.f) - mu * mu + EPSLN);
    #pragma unroll
    for (int c = 0; c < 32; ++c) h[c] = leaky((h[c] - mu) * rstd * pe_g1[c] + pe_be1[c]);

    // ---- PE layer 2: 32 -> 32, LN (no leaky) -> fpe ----
    float f[32];
    #pragma unroll
    for (int c = 0; c < 32; ++c) f[c] = pe_b2[c];
    #pragma unroll
    for (int j = 0; j < 32; ++j) {
        float hj = h[j];
        #pragma unroll
        for (int c = 0; c < 32; ++c) f[c] += hj * pe_w2[j * 32 + c];
    }
    s = 0.f; q = 0.f;
    #pragma unroll
    for (int c = 0; c < 32; ++c) { s += f[c]; q += f[c] * f[c]; }
    mu = s * (1.f / 32.f);
    rstd = rsqrtf(q * (1.f / 32.f) - mu * mu + EPSLN);
    {
        unsigned short* fp = fpe + (size_t)e * 32;
        #pragma unroll
        for (int i = 0; i < 4; ++i) {
            short8 v;
            #pragma unroll
            for (int j = 0; j < 8; ++j) {
                int c = i * 8 + j;
                v[j] = (short)f2bf((f[c] - mu) * rstd * pe_g2[c] + pe_be2[c]);
            }
            *(short8*)(fp + i * 8) = v;
        }
    }

    // ---- WN layer 1: 3 -> 16, LN, leaky ----
    float w1[16];
    s = 0.f; q = 0.f;
    #pragma unroll
    for (int c = 0; c < 16; ++c) {
        float v = wn_b1[c] + lx * wn_w1[c] + ly * wn_w1[16 + c] + lz * wn_w1[32 + c];
        w1[c] = v; s += v; q += v * v;
    }
    mu = s * (1.f / 16.f);
    rstd = rsqrtf(q * (1.f / 16.f) - mu * mu + EPSLN);
    #pragma unroll
    for (int c = 0; c < 16; ++c) w1[c] = leaky((w1[c] - mu) * rstd * wn_g1[c] + wn_be1[c]);

    // ---- WN layer 2: 16 -> 16, LN, leaky ----
    float w2[16];
    #pragma unroll
    for (int c = 0; c < 16; ++c) w2[c] = wn_b2[c];
    #pragma unroll
    for (int j = 0; j < 16; ++j) {
        float wj = w1[j];
        #pragma unroll
        for (int c = 0; c < 16; ++c) w2[c] += wj * wn_w2[j * 16 + c];
    }
    s = 0.f; q = 0.f;
    #pragma unroll
    for (int c = 0; c < 16; ++c) { s += w2[c]; q += w2[c] * w2[c]; }
    mu = s * (1.f / 16.f);
    rstd = rsqrtf(q * (1.f / 16.f) - mu * mu + EPSLN);
    #pragma unroll
    for (int c = 0; c < 16; ++c) w2[c] = leaky((w2[c] - mu) * rstd * wn_g2[c] + wn_be2[c]);

    // ---- folded LN(256) stats for wn3: mu3, r from quadratic form ----
    float mu3 = st[288];
    #pragma unroll
    for (int hh = 0; hh < 16; ++hh) mu3 += w2[hh] * st[256 + hh];
    float esq = st[289];
    #pragma unroll
    for (int hh = 0; hh < 16; ++hh) {
        float acc = 2.f * st[272 + hh];
        #pragma unroll
        for (int hp = 0; hp < 16; ++hp) acc += st[hh * 16 + hp] * w2[hp];
        esq += w2[hh] * acc;
    }
    float r3 = rsqrtf(esq - mu3 * mu3 + EPSLN);

    // ---- store Ut (transposed per point) ----
    float* up = Ut + (size_t)m * 288;
    #pragma unroll
    for (int hh = 0; hh < 16; ++hh) up[hh * 16 + k] = w2[hh];
    up[256 + k] = r3;
    up[272 + k] = mu3;
}

// ---------------------------------------------------------------------------
// Phase B: wave-per-point. raw[k][c] = wh2 @ W3 recomputed per lane (4 c's),
// wh2/r/mu via SGPR loads, W3 from LDS. Fused gather-multiply + pe-sum +
// LN(288) with a single butterfly. -> xln bf16.
// ---------------------------------------------------------------------------
__global__ __launch_bounds__(256) void edge_agg_kernel(
    const float* __restrict__ feats, const int* __restrict__ nei,
    const float* __restrict__ Ut, const unsigned short* __restrict__ fpe,
    const float* __restrict__ wn_w3, const float* __restrict__ wn_b3,
    const float* __restrict__ wn_g3, const float* __restrict__ wn_be3,
    const float* __restrict__ nm_g, const float* __restrict__ nm_b,
    unsigned short* __restrict__ xln)
{
    __shared__ float W3s[16 * 256];
    const int t = threadIdx.x;
    #pragma unroll
    for (int i = 0; i < 16; ++i) W3s[t + 256 * i] = wn_w3[t + 256 * i];
    __syncthreads();

    const int lane = t & 63;
    const int p = __builtin_amdgcn_readfirstlane(blockIdx.x * 4 + (t >> 6));
    const float* up = Ut + (size_t)p * 288;
    const int* np = nei + p * KNB;
    int idxk[KNB];
    #pragma unroll
    for (int k = 0; k < KNB; ++k) idxk[k] = np[k];

    const int c0 = lane * 4;

    float raw[KNB][4];
    #pragma unroll
    for (int k = 0; k < KNB; ++k)
        #pragma unroll
        for (int j = 0; j < 4; ++j) raw[k][j] = 0.f;

    #pragma unroll
    for (int hh = 0; hh < 16; ++hh) {
        f32x4 w3r = *(const f32x4*)&W3s[hh * 256 + c0];
        #pragma unroll
        for (int k = 0; k < KNB; ++k) {
            float u = up[hh * 16 + k];   // wave-uniform -> SGPR
            raw[k][0] += u * w3r[0];
            raw[k][1] += u * w3r[1];
            raw[k][2] += u * w3r[2];
            raw[k][3] += u * w3r[3];
        }
    }

    f32x4 b3r = *(const f32x4*)(wn_b3 + c0);
    f32x4 g3r = *(const f32x4*)(wn_g3 + c0);
    f32x4 be3r = *(const f32x4*)(wn_be3 + c0);
    float agg[4] = {0.f, 0.f, 0.f, 0.f};
    #pragma unroll
    for (int k = 0; k < KNB; ++k) {
        float rk = up[256 + k];
        float muk = up[272 + k];
        f32x4 fv = *(const f32x4*)(feats + (size_t)idxk[k] * CINC + c0);
        #pragma unroll
        for (int j = 0; j < 4; ++j) {
            float w3 = (raw[k][j] + b3r[j] - muk) * rk * g3r[j] + be3r[j];
            agg[j] += fv[j] * w3;
        }
    }

    // pe channel sums (lanes 0..31)
    float pv = 0.f;
    if (lane < 32) {
        #pragma unroll
        for (int k = 0; k < KNB; ++k)
            pv += bf2f(fpe[((size_t)p * KNB + k) * 32 + lane]);
    }

    // LN(288): one butterfly over the wave
    float s = agg[0] + agg[1] + agg[2] + agg[3];
    float q = agg[0] * agg[0] + agg[1] * agg[1] + agg[2] * agg[2] + agg[3] * agg[3];
    if (lane < 32) { s += pv; q += pv * pv; }
    #pragma unroll
    for (int off = 1; off < 64; off <<= 1) {
        s += __shfl_xor(s, off);
        q += __shfl_xor(q, off);
    }
    float mu = s * (1.f / 288.f);
    float rstd = rsqrtf(q * (1.f / 288.f) - mu * mu + EPSLN);

    unsigned short* xp = xln + (size_t)p * CMID;
    ushort4 o;
    o.x = f2bf((agg[0] - mu) * rstd * nm_g[c0 + 0] + nm_b[c0 + 0]);
    o.y = f2bf((agg[1] - mu) * rstd * nm_g[c0 + 1] + nm_b[c0 + 1]);
    o.z = f2bf((agg[2] - mu) * rstd * nm_g[c0 + 2] + nm_b[c0 + 2]);
    o.w = f2bf((agg[3] - mu) * rstd * nm_g[c0 + 3] + nm_b[c0 + 3]);
    *(ushort4*)(xp + c0) = o;
    if (lane < 32)
        xp[256 + lane] = f2bf((pv - mu) * rstd * nm_g[256 + lane] + nm_b[256 + lane]);
}

// ---------------------------------------------------------------------------
// Conversion kernels
// ---------------------------------------------------------------------------
__global__ __launch_bounds__(256) void transpose_bf16_kernel(
    const float* __restrict__ src, unsigned short* __restrict__ dst, int K, int N)
{
    __shared__ float tile[32][33];
    const int k0 = blockIdx.y * 32, n0 = blockIdx.x * 32;
    const int tx = threadIdx.x & 31, ty = threadIdx.x >> 5;
    #pragma unroll
    for (int i = ty; i < 32; i += 8)
        tile[i][tx] = src[(size_t)(k0 + i) * N + n0 + tx];
    __syncthreads();
    #pragma unroll
    for (int i = ty; i < 32; i += 8)
        dst[(size_t)(n0 + i) * K + k0 + tx] = f2bf(tile[tx][i]);
}

__global__ __launch_bounds__(256) void feats_bf16_kernel(
    const float* __restrict__ src, unsigned short* __restrict__ dst)
{
    int i = (blockIdx.x * 256 + threadIdx.x) * 4;
    float4 v = *(const float4*)(src + i);
    ushort4 o;
    o.x = f2bf(v.x); o.y = f2bf(v.y); o.z = f2bf(v.z); o.w = f2bf(v.w);
    *(ushort4*)(dst + i) = o;
}

// ---------------------------------------------------------------------------
// GEMM 1: h1 = leaky(xln @ l1_w + l1_b), bf16 MFMA, 128x128, BK=32
// ---------------------------------------------------------------------------
__global__ __launch_bounds__(256) void gemm1_mfma(
    const unsigned short* __restrict__ A,
    const unsigned short* __restrict__ BT,
    const float* __restrict__ bias,
    unsigned short* __restrict__ C)
{
    __shared__ unsigned short As[128 * 32];
    __shared__ unsigned short Bs[128 * 32];
    const int t = threadIdx.x;
    const int lane = t & 63, wave = t >> 6;
    const int wm = wave >> 1, wn = wave & 1;
    const int m0 = blockIdx.y * 128, n0 = blockIdx.x * 128;
    const int l15 = lane & 15, j0 = (lane >> 4) << 3;

    f32x4 zero = {0.f, 0.f, 0.f, 0.f};
    f32x4 acc[4][4];
    #pragma unroll
    for (int i = 0; i < 4; ++i)
        #pragma unroll
        for (int j = 0; j < 4; ++j) acc[i][j] = zero;

    for (int kt = 0; kt < CMID; kt += 32) {
        stage_tile(A,  CMID, m0, kt, As, wave, lane);
        stage_tile(BT, CMID, n0, kt, Bs, wave, lane);
        __syncthreads();
        short8 af[4], bf[4];
        #pragma unroll
        for (int i = 0; i < 4; ++i) {
            int ar = wm * 64 + i * 16 + l15;
            af[i] = *(const short8*)&As[ar * 32 + (j0 ^ ((ar & 3) << 3))];
            int br = wn * 64 + i * 16 + l15;
            bf[i] = *(const short8*)&Bs[br * 32 + (j0 ^ ((br & 3) << 3))];
        }
        #pragma unroll
        for (int i = 0; i < 4; ++i)
            #pragma unroll
            for (int j = 0; j < 4; ++j)
                acc[i][j] = __builtin_amdgcn_mfma_f32_16x16x32_bf16(af[i], bf[j], acc[i][j], 0, 0, 0);
        __syncthreads();
    }

    const int q = lane >> 4;
    #pragma unroll
    for (int j = 0; j < 4; ++j) {
        int ncol = n0 + wn * 64 + j * 16 + l15;
        float bv = bias[ncol];
        #pragma unroll
        for (int i = 0; i < 4; ++i) {
            int mbase = m0 + wm * 64 + i * 16 + q * 4;
            #pragma unroll
            for (int r = 0; r < 4; ++r)
                C[(size_t)(mbase + r) * L1OUT + ncol] = f2bf(leaky(acc[i][j][r] + bv));
        }
    }
}

// ---------------------------------------------------------------------------
// GEMM 2: out = leaky(h1 @ l2_w + feats @ sc_w + b2 + bsc), dual-K bf16 MFMA
// ---------------------------------------------------------------------------
__global__ __launch_bounds__(256) void gemm2_mfma(
    const unsigned short* __restrict__ H,
    const unsigned short* __restrict__ W2T,
    const unsigned short* __restrict__ F,
    const unsigned short* __restrict__ WscT,
    const float* __restrict__ b2, const float* __restrict__ bsc,
    float* __restrict__ Out)
{
    __shared__ unsigned short As[128 * 32];
    __shared__ unsigned short Bs[128 * 32];
    const int t = threadIdx.x;
    const int lane = t & 63, wave = t >> 6;
    const int wm = wave >> 1, wn = wave & 1;
    const int m0 = blockIdx.y * 128, n0 = blockIdx.x * 128;
    const int l15 = lane & 15, j0 = (lane >> 4) << 3;

    f32x4 zero = {0.f, 0.f, 0.f, 0.f};
    f32x4 acc[4][4];
    #pragma unroll
    for (int i = 0; i < 4; ++i)
        #pragma unroll
        for (int j = 0; j < 4; ++j) acc[i][j] = zero;

    for (int kt = 0; kt < L1OUT; kt += 32) {
        stage_tile(H,   L1OUT, m0, kt, As, wave, lane);
        stage_tile(W2T, L1OUT, n0, kt, Bs, wave, lane);
        __syncthreads();
        short8 af[4], bf[4];
        #pragma unroll
        for (int i = 0; i < 4; ++i) {
            int ar = wm * 64 + i * 16 + l15;
            af[i] = *(const short8*)&As[ar * 32 + (j0 ^ ((ar & 3) << 3))];
            int br = wn * 64 + i * 16 + l15;
            bf[i] = *(const short8*)&Bs[br * 32 + (j0 ^ ((br & 3) << 3))];
        }
        #pragma unroll
        for (int i = 0; i < 4; ++i)
            #pragma unroll
            for (int j = 0; j < 4; ++j)
                acc[i][j] = __builtin_amdgcn_mfma_f32_16x16x32_bf16(af[i], bf[j], acc[i][j], 0, 0, 0);
        __syncthreads();
    }
    for (int kt = 0; kt < CINC; kt += 32) {
        stage_tile(F,    CINC, m0, kt, As, wave, lane);
        stage_tile(WscT, CINC, n0, kt, Bs, wave, lane);
        __syncthreads();
        short8 af[4], bf[4];
        #pragma unroll
        for (int i = 0; i < 4; ++i) {
            int ar = wm * 64 + i * 16 + l15;
            af[i] = *(const short8*)&As[ar * 32 + (j0 ^ ((ar & 3) << 3))];
            int br = wn * 64 + i * 16 + l15;
            bf[i] = *(const short8*)&Bs[br * 32 + (j0 ^ ((br & 3) << 3))];
        }
        #pragma unroll
        for (int i = 0; i < 4; ++i)
            #pragma unroll
            for (int j = 0; j < 4; ++j)
                acc[i][j] = __builtin_amdgcn_mfma_f32_16x16x32_bf16(af[i], bf[j], acc[i][j], 0, 0, 0);
        __syncthreads();
    }

    const int q = lane >> 4;
    #pragma unroll
    for (int j = 0; j < 4; ++j) {
        int ncol = n0 + wn * 64 + j * 16 + l15;
        float bv = b2[ncol] + bsc[ncol];
        #pragma unroll
        for (int i = 0; i < 4; ++i) {
            int mbase = m0 + wm * 64 + i * 16 + q * 4;
            #pragma unroll
            for (int r = 0; r < 4; ++r)
                Out[(size_t)(mbase + r) * COUTC + ncol] = leaky(acc[i][j][r] + bv);
        }
    }
}

extern "C" void kernel_launch(void* const* d_in, const int* in_sizes, int n_in,
                              void* d_out, int out_size, void* d_ws, size_t ws_size,
                              hipStream_t stream)
{
    const float* xyz    = (const float*)d_in[0];
    const float* feats  = (const float*)d_in[1];
    const int*   nei    = (const int*)d_in[2];
    const float* pe_w1  = (const float*)d_in[3];
    const float* pe_b1  = (const float*)d_in[4];
    const float* pe_g1  = (const float*)d_in[5];
    const float* pe_be1 = (const float*)d_in[6];
    const float* pe_w2  = (const float*)d_in[7];
    const float* pe_b2  = (const float*)d_in[8];
    const float* pe_g2  = (const float*)d_in[9];
    const float* pe_be2 = (const float*)d_in[10];
    const float* wn_w1  = (const float*)d_in[11];
    const float* wn_b1  = (const float*)d_in[12];
    const float* wn_g1  = (const float*)d_in[13];
    const float* wn_be1 = (const float*)d_in[14];
    const float* wn_w2  = (const float*)d_in[15];
    const float* wn_b2  = (const float*)d_in[16];
    const float* wn_g2  = (const float*)d_in[17];
    const float* wn_be2 = (const float*)d_in[18];
    const float* wn_w3  = (const float*)d_in[19];
    const float* wn_b3  = (const float*)d_in[20];
    const float* wn_g3  = (const float*)d_in[21];
    const float* wn_be3 = (const float*)d_in[22];
    const float* nm_g   = (const float*)d_in[23];
    const float* nm_b   = (const float*)d_in[24];
    const float* l1_w   = (const float*)d_in[25];
    const float* l1_b   = (const float*)d_in[26];
    const float* l2_w   = (const float*)d_in[27];
    const float* l2_b   = (const float*)d_in[28];
    const float* sc_w   = (const float*)d_in[29];
    const float* sc_b   = (const float*)d_in[30];

    char* ws = (char*)d_ws;
    // persistent across whole call:
    unsigned short* xln    = (unsigned short*)(ws);               // 18,874,368
    unsigned short* featsb = (unsigned short*)(ws + 18874368);    // 16,777,216
    unsigned short* l1_wT  = (unsigned short*)(ws + 35651584);    //    589,824
    unsigned short* l2_wT  = (unsigned short*)(ws + 36241408);    //  1,048,576
    unsigned short* sc_wT  = (unsigned short*)(ws + 37289984);    //    262,144
    float*          st     = (float*)(ws + 37552128);             //      4,096 (pad)
    // union region @ 37,556,224: {fpe 33.5MB + Ut 37.7MB} then reused by h1 67.1MB
    unsigned short* fpe    = (unsigned short*)(ws + 37556224);
    float*          Ut     = (float*)(ws + 71110656);
    unsigned short* h1     = (unsigned short*)(ws + 37556224);

    // small prep
    wn3_stats_kernel<<<1, 256, 0, stream>>>(wn_w3, wn_b3, st);
    transpose_bf16_kernel<<<dim3(L1OUT / 32, CMID / 32), 256, 0, stream>>>(l1_w, l1_wT, CMID, L1OUT);
    transpose_bf16_kernel<<<dim3(COUTC / 32, L1OUT / 32), 256, 0, stream>>>(l2_w, l2_wT, L1OUT, COUTC);
    transpose_bf16_kernel<<<dim3(COUTC / 32, CINC / 32), 256, 0, stream>>>(sc_w, sc_wT, CINC, COUTC);
    feats_bf16_kernel<<<(NPTS * CINC / 4) / 256, 256, 0, stream>>>(feats, featsb);

    // edge stage
    edge_mlp_kernel<<<(NPTS * KNB) / 256, 256, 0, stream>>>(
        xyz, nei,
        pe_w1, pe_b1, pe_g1, pe_be1, pe_w2, pe_b2, pe_g2, pe_be2,
        wn_w1, wn_b1, wn_g1, wn_be1, wn_w2, wn_b2, wn_g2, wn_be2,
        st, fpe, Ut);

    edge_agg_kernel<<<NPTS / 4, 256, 0, stream>>>(
        feats, nei, Ut, fpe, wn_w3, wn_b3, wn_g3, wn_be3, nm_g, nm_b, xln);

    // GEMMs (h1 reuses the fpe/Ut region — they are dead after edge_agg)
    gemm1_mfma<<<dim3(L1OUT / 128, NPTS / 128), 256, 0, stream>>>(xln, l1_wT, l1_b, h1);

    gemm2_mfma<<<dim3(COUTC / 128, NPTS / 128), 256, 0, stream>>>(
        h1, l2_wT, featsb, sc_wT, l2_b, sc_b, (float*)d_out);
}

// Round 6
// 548.437 us; speedup vs baseline: 2.4396x; 1.0196x over previous
//
#include <hip/hip_runtime.h>

#define NPTS  32768
#define KNB   16
#define CINC  256
#define PEC   32
#define HWN   16
#define CMID  288
#define L1OUT 1024
#define COUTC 512
#define EPSLN 1e-5f
#define PBLK  16

typedef __attribute__((ext_vector_type(8))) short short8;
typedef __attribute__((ext_vector_type(4))) float f32x4;

__device__ __forceinline__ float leaky(float x) { return x > 0.f ? x : 0.1f * x; }

__device__ __forceinline__ float bf2f(unsigned short u) {
    union { unsigned int i; float f; } x; x.i = ((unsigned int)u) << 16; return x.f;
}
__device__ __forceinline__ unsigned short f2bf(float f) {
    unsigned int x = __float_as_uint(f);
    x = (x + 0x7fffu + ((x >> 16) & 1u)) >> 16;
    return (unsigned short)x;
}

// async global->LDS, 16B per lane, dest = wave-uniform base + lane*16
__device__ __forceinline__ void gld_lds16(const unsigned short* g, unsigned short* l) {
    __builtin_amdgcn_global_load_lds(
        (const __attribute__((address_space(1))) unsigned int*)g,
        (__attribute__((address_space(3))) unsigned int*)l,
        16, 0, 0);
}

__device__ __forceinline__ void stage_tile(const unsigned short* __restrict__ g,
                                           size_t ld, int row0, int k0,
                                           unsigned short* lds, int wave, int lane)
{
    #pragma unroll
    for (int r = 0; r < 2; ++r) {
        int e   = r * 2048 + wave * 512 + lane * 8;
        int row = e >> 5;
        int kp  = e & 31;
        int kl  = kp ^ ((row & 3) << 3);
        const unsigned short* src = g + (size_t)(row0 + row) * ld + (k0 + kl);
        gld_lds16(src, lds + r * 2048 + wave * 512);
    }
}

// ---------------------------------------------------------------------------
// Stats kernel: folded LN(256) statistics of wn3 as a quadratic form in wh2.
// st layout: G @0 (256), wm3 @256 (16), gb @272 (16), bm3 @288, bsq @289.
// ---------------------------------------------------------------------------
__global__ __launch_bounds__(256) void wn3_stats_kernel(
    const float* __restrict__ W3, const float* __restrict__ b3, float* __restrict__ st)
{
    int t = threadIdx.x;
    int h = t >> 4, hp = t & 15;
    float g = 0.f;
    for (int c = 0; c < CINC; ++c) g += W3[h * CINC + c] * W3[hp * CINC + c];
    st[t] = g * (1.f / CINC);
    if (t < 16) {
        float s = 0.f, sb = 0.f;
        for (int c = 0; c < CINC; ++c) { float w = W3[t * CINC + c]; s += w; sb += w * b3[c]; }
        st[256 + t] = s * (1.f / CINC);
        st[272 + t] = sb * (1.f / CINC);
    }
    if (t == 0) {
        float s = 0.f, q = 0.f;
        for (int c = 0; c < CINC; ++c) { float b = b3[c]; s += b; q += b * b; }
        st[288] = s * (1.f / CINC);
        st[289] = q * (1.f / CINC);
    }
}

// packed small-weight LDS offsets (floats)
#define PEW1  0
#define PEB1  96
#define PEG1  128
#define PEBE1 160
#define PEW2  192
#define PEB2  1216
#define PEG2  1248
#define PEBE2 1280
#define WNW1  1312
#define WNB1  1360
#define WNG1  1376
#define WNBE1 1392
#define WNW2  1408
#define WNB2  1664
#define WNG2  1680
#define WNBE2 1696
#define STO   1712
// total 2002 -> round to 2008

// ---------------------------------------------------------------------------
// Fused edge kernel: 16 points per 256-thread block.
// Phase A (thread = edge): PE MLP (pe-sum via shfl butterfly), WN MLP,
//   folded LN(256) stats -> LDS (w2s/rms/mus/pes).
// Phase B (wave = point, 4 points each): raw = w2 @ W3 from LDS, normalize,
//   bf16 feats gather-multiply, LN(288) butterfly -> xln bf16.
// ---------------------------------------------------------------------------
__global__ __launch_bounds__(256) void edge_fused_kernel(
    const float* __restrict__ xyz, const unsigned short* __restrict__ featsb,
    const int* __restrict__ nei,
    const float* __restrict__ pe_w1, const float* __restrict__ pe_b1,
    const float* __restrict__ pe_g1, const float* __restrict__ pe_be1,
    const float* __restrict__ pe_w2, const float* __restrict__ pe_b2,
    const float* __restrict__ pe_g2, const float* __restrict__ pe_be2,
    const float* __restrict__ wn_w1, const float* __restrict__ wn_b1,
    const float* __restrict__ wn_g1, const float* __restrict__ wn_be1,
    const float* __restrict__ wn_w2, const float* __restrict__ wn_b2,
    const float* __restrict__ wn_g2, const float* __restrict__ wn_be2,
    const float* __restrict__ st,
    const float* __restrict__ wn_w3, const float* __restrict__ wn_b3,
    const float* __restrict__ wn_g3, const float* __restrict__ wn_be3,
    const float* __restrict__ nm_g, const float* __restrict__ nm_b,
    unsigned short* __restrict__ xln)
{
    __shared__ __align__(16) float Ws[2008];
    __shared__ __align__(16) float W3s[16 * 256];
    __shared__ __align__(16) float w2s[PBLK * 256];   // [lp][hh][k]
    __shared__ float rms[PBLK * 16], mus[PBLK * 16], pes[PBLK * 32];

    const int t = threadIdx.x;

    // ---- stage weights + stats into LDS ----
    if (t < 96) Ws[PEW1 + t] = pe_w1[t];
    if (t < 32) {
        Ws[PEB1 + t] = pe_b1[t];  Ws[PEG1 + t] = pe_g1[t];  Ws[PEBE1 + t] = pe_be1[t];
        Ws[PEB2 + t] = pe_b2[t];  Ws[PEG2 + t] = pe_g2[t];  Ws[PEBE2 + t] = pe_be2[t];
    }
    #pragma unroll
    for (int i = t; i < 1024; i += 256) Ws[PEW2 + i] = pe_w2[i];
    if (t < 48) Ws[WNW1 + t] = wn_w1[t];
    // BUGFIX (R5): wn_w2 (256 floats) was never staged — WN layer 2 read
    // uninitialized LDS. This was the real cause of the R4/R5 absmax ~0.71.
    Ws[WNW2 + t] = wn_w2[t];
    if (t < 16) {
        Ws[WNB1 + t] = wn_b1[t];  Ws[WNG1 + t] = wn_g1[t];  Ws[WNBE1 + t] = wn_be1[t];
        Ws[WNB2 + t] = wn_b2[t];  Ws[WNG2 + t] = wn_g2[t];  Ws[WNBE2 + t] = wn_be2[t];
    }
    // BUGFIX (R4): st has 290 entries but only 256 threads — must stride.
    for (int i = t; i < 290; i += 256) Ws[STO + i] = st[i];
    #pragma unroll
    for (int i = t; i < 4096; i += 256) W3s[i] = wn_w3[i];
    __syncthreads();

    // ======================= Phase A: per-edge MLPs =======================
    {
        const int lp = t >> 4, kk = t & 15;
        const int m = blockIdx.x * PBLK + lp;
        const int n = nei[m * KNB + kk];
        const float lx = xyz[n * 3 + 0] - xyz[m * 3 + 0];
        const float ly = xyz[n * 3 + 1] - xyz[m * 3 + 1];
        const float lz = xyz[n * 3 + 2] - xyz[m * 3 + 2];

        // ---- PE layer 1: 3 -> 32, LN, leaky ----
        float h[32];
        float s = 0.f, q = 0.f;
        #pragma unroll
        for (int c4 = 0; c4 < 8; ++c4) {
            f32x4 wa = *(const f32x4*)&Ws[PEW1 + c4 * 4];
            f32x4 wb = *(const f32x4*)&Ws[PEW1 + 32 + c4 * 4];
            f32x4 wc = *(const f32x4*)&Ws[PEW1 + 64 + c4 * 4];
            f32x4 bb = *(const f32x4*)&Ws[PEB1 + c4 * 4];
            #pragma unroll
            for (int j = 0; j < 4; ++j) {
                float v = bb[j] + lx * wa[j] + ly * wb[j] + lz * wc[j];
                h[c4 * 4 + j] = v; s += v; q += v * v;
            }
        }
        float mu = s * (1.f / 32.f);
        float rstd = rsqrtf(q * (1.f / 32.f) - mu * mu + EPSLN);
        #pragma unroll
        for (int c4 = 0; c4 < 8; ++c4) {
            f32x4 g = *(const f32x4*)&Ws[PEG1 + c4 * 4];
            f32x4 be = *(const f32x4*)&Ws[PEBE1 + c4 * 4];
            #pragma unroll
            for (int j = 0; j < 4; ++j) {
                int c = c4 * 4 + j;
                h[c] = leaky((h[c] - mu) * rstd * g[j] + be[j]);
            }
        }

        // ---- PE layer 2: 32 -> 32, LN ----
        float f[32];
        #pragma unroll
        for (int c4 = 0; c4 < 8; ++c4) {
            f32x4 bb = *(const f32x4*)&Ws[PEB2 + c4 * 4];
            f[c4 * 4 + 0] = bb[0]; f[c4 * 4 + 1] = bb[1];
            f[c4 * 4 + 2] = bb[2]; f[c4 * 4 + 3] = bb[3];
        }
        #pragma unroll
        for (int j = 0; j < 32; ++j) {
            float hj = h[j];
            #pragma unroll
            for (int c4 = 0; c4 < 8; ++c4) {
                f32x4 w = *(const f32x4*)&Ws[PEW2 + j * 32 + c4 * 4];
                f[c4 * 4 + 0] += hj * w[0]; f[c4 * 4 + 1] += hj * w[1];
                f[c4 * 4 + 2] += hj * w[2]; f[c4 * 4 + 3] += hj * w[3];
            }
        }
        s = 0.f; q = 0.f;
        #pragma unroll
        for (int c = 0; c < 32; ++c) { s += f[c]; q += f[c] * f[c]; }
        mu = s * (1.f / 32.f);
        rstd = rsqrtf(q * (1.f / 32.f) - mu * mu + EPSLN);
        // normalize + butterfly-sum over the 16 edges (consecutive lanes) -> pes
        #pragma unroll
        for (int c4 = 0; c4 < 8; ++c4) {
            f32x4 g = *(const f32x4*)&Ws[PEG2 + c4 * 4];
            f32x4 be = *(const f32x4*)&Ws[PEBE2 + c4 * 4];
            #pragma unroll
            for (int j = 0; j < 4; ++j) {
                int c = c4 * 4 + j;
                float v = (f[c] - mu) * rstd * g[j] + be[j];
                v += __shfl_xor(v, 1);
                v += __shfl_xor(v, 2);
                v += __shfl_xor(v, 4);
                v += __shfl_xor(v, 8);
                if (kk == 0) pes[lp * 32 + c] = v;
            }
        }

        // ---- WN layer 1: 3 -> 16, LN, leaky ----
        float w1[16];
        s = 0.f; q = 0.f;
        #pragma unroll
        for (int c4 = 0; c4 < 4; ++c4) {
            f32x4 wa = *(const f32x4*)&Ws[WNW1 + c4 * 4];
            f32x4 wb = *(const f32x4*)&Ws[WNW1 + 16 + c4 * 4];
            f32x4 wc = *(const f32x4*)&Ws[WNW1 + 32 + c4 * 4];
            f32x4 bb = *(const f32x4*)&Ws[WNB1 + c4 * 4];
            #pragma unroll
            for (int j = 0; j < 4; ++j) {
                float v = bb[j] + lx * wa[j] + ly * wb[j] + lz * wc[j];
                w1[c4 * 4 + j] = v; s += v; q += v * v;
            }
        }
        mu = s * (1.f / 16.f);
        rstd = rsqrtf(q * (1.f / 16.f) - mu * mu + EPSLN);
        #pragma unroll
        for (int c4 = 0; c4 < 4; ++c4) {
            f32x4 g = *(const f32x4*)&Ws[WNG1 + c4 * 4];
            f32x4 be = *(const f32x4*)&Ws[WNBE1 + c4 * 4];
            #pragma unroll
            for (int j = 0; j < 4; ++j) {
                int c = c4 * 4 + j;
                w1[c] = leaky((w1[c] - mu) * rstd * g[j] + be[j]);
            }
        }

        // ---- WN layer 2: 16 -> 16, LN, leaky ----
        float w2[16];
        #pragma unroll
        for (int c4 = 0; c4 < 4; ++c4) {
            f32x4 bb = *(const f32x4*)&Ws[WNB2 + c4 * 4];
            w2[c4 * 4 + 0] = bb[0]; w2[c4 * 4 + 1] = bb[1];
            w2[c4 * 4 + 2] = bb[2]; w2[c4 * 4 + 3] = bb[3];
        }
        #pragma unroll
        for (int j = 0; j < 16; ++j) {
            float wj = w1[j];
            #pragma unroll
            for (int c4 = 0; c4 < 4; ++c4) {
                f32x4 w = *(const f32x4*)&Ws[WNW2 + j * 16 + c4 * 4];
                w2[c4 * 4 + 0] += wj * w[0]; w2[c4 * 4 + 1] += wj * w[1];
                w2[c4 * 4 + 2] += wj * w[2]; w2[c4 * 4 + 3] += wj * w[3];
            }
        }
        s = 0.f; q = 0.f;
        #pragma unroll
        for (int c = 0; c < 16; ++c) { s += w2[c]; q += w2[c] * w2[c]; }
        mu = s * (1.f / 16.f);
        rstd = rsqrtf(q * (1.f / 16.f) - mu * mu + EPSLN);
        #pragma unroll
        for (int c4 = 0; c4 < 4; ++c4) {
            f32x4 g = *(const f32x4*)&Ws[WNG2 + c4 * 4];
            f32x4 be = *(const f32x4*)&Ws[WNBE2 + c4 * 4];
            #pragma unroll
            for (int j = 0; j < 4; ++j) {
                int c = c4 * 4 + j;
                w2[c] = leaky((w2[c] - mu) * rstd * g[j] + be[j]);
            }
        }

        // ---- folded LN(256) stats ----
        float mu3 = Ws[STO + 288];
        #pragma unroll
        for (int h4 = 0; h4 < 4; ++h4) {
            f32x4 wm = *(const f32x4*)&Ws[STO + 256 + h4 * 4];
            mu3 += w2[h4 * 4 + 0] * wm[0] + w2[h4 * 4 + 1] * wm[1]
                 + w2[h4 * 4 + 2] * wm[2] + w2[h4 * 4 + 3] * wm[3];
        }
        float esq = Ws[STO + 289];
        #pragma unroll
        for (int hh = 0; hh < 16; ++hh) {
            float acc = 2.f * Ws[STO + 272 + hh];
            #pragma unroll
            for (int h4 = 0; h4 < 4; ++h4) {
                f32x4 g = *(const f32x4*)&Ws[STO + hh * 16 + h4 * 4];
                acc += g[0] * w2[h4 * 4 + 0] + g[1] * w2[h4 * 4 + 1]
                     + g[2] * w2[h4 * 4 + 2] + g[3] * w2[h4 * 4 + 3];
            }
            esq += w2[hh] * acc;
        }
        float r3 = rsqrtf(esq - mu3 * mu3 + EPSLN);

        #pragma unroll
        for (int hh = 0; hh < 16; ++hh) w2s[lp * 256 + hh * 16 + kk] = w2[hh];
        rms[lp * 16 + kk] = r3;
        mus[lp * 16 + kk] = mu3;
    }
    __syncthreads();

    // ======================= Phase B: per-point aggregation ================
    const int lane = t & 63, wave = t >> 6;
    const int c0 = lane * 4;
    const f32x4 b3r  = *(const f32x4*)(wn_b3 + c0);
    const f32x4 g3r  = *(const f32x4*)(wn_g3 + c0);
    const f32x4 be3r = *(const f32x4*)(wn_be3 + c0);
    const f32x4 ngr  = *(const f32x4*)(nm_g + c0);
    const f32x4 nbr  = *(const f32x4*)(nm_b + c0);
    const float ng2  = (lane < 32) ? nm_g[256 + lane] : 0.f;
    const float nb2  = (lane < 32) ? nm_b[256 + lane] : 0.f;

    for (int pp = 0; pp < 4; ++pp) {
        const int lp = wave * 4 + pp;
        const int p  = blockIdx.x * PBLK + lp;
        const int* np = nei + p * KNB;

        float raw[KNB][4];
        #pragma unroll
        for (int k = 0; k < KNB; ++k)
            #pragma unroll
            for (int j = 0; j < 4; ++j) raw[k][j] = 0.f;

        #pragma unroll
        for (int hh = 0; hh < 16; ++hh) {
            f32x4 w3r = *(const f32x4*)&W3s[hh * 256 + c0];
            const float* w2p = &w2s[lp * 256 + hh * 16];
            float uu[16];
            *(f32x4*)&uu[0]  = *(const f32x4*)&w2p[0];
            *(f32x4*)&uu[4]  = *(const f32x4*)&w2p[4];
            *(f32x4*)&uu[8]  = *(const f32x4*)&w2p[8];
            *(f32x4*)&uu[12] = *(const f32x4*)&w2p[12];
            #pragma unroll
            for (int k = 0; k < KNB; ++k) {
                raw[k][0] += uu[k] * w3r[0];
                raw[k][1] += uu[k] * w3r[1];
                raw[k][2] += uu[k] * w3r[2];
                raw[k][3] += uu[k] * w3r[3];
            }
        }

        float agg[4] = {0.f, 0.f, 0.f, 0.f};
        #pragma unroll
        for (int k = 0; k < KNB; ++k) {
            int nk = np[k];
            float rk  = rms[lp * 16 + k];
            float muk = mus[lp * 16 + k];
            ushort4 fu = *(const ushort4*)(featsb + (size_t)nk * CINC + c0);
            float w3x = (raw[k][0] + b3r[0] - muk) * rk * g3r[0] + be3r[0];
            float w3y = (raw[k][1] + b3r[1] - muk) * rk * g3r[1] + be3r[1];
            float w3z = (raw[k][2] + b3r[2] - muk) * rk * g3r[2] + be3r[2];
            float w3w = (raw[k][3] + b3r[3] - muk) * rk * g3r[3] + be3r[3];
            agg[0] += bf2f(fu.x) * w3x;
            agg[1] += bf2f(fu.y) * w3y;
            agg[2] += bf2f(fu.z) * w3z;
            agg[3] += bf2f(fu.w) * w3w;
        }

        float pv = (lane < 32) ? pes[lp * 32 + lane] : 0.f;

        float s = agg[0] + agg[1] + agg[2] + agg[3];
        float q = agg[0] * agg[0] + agg[1] * agg[1] + agg[2] * agg[2] + agg[3] * agg[3];
        if (lane < 32) { s += pv; q += pv * pv; }
        #pragma unroll
        for (int off = 1; off < 64; off <<= 1) {
            s += __shfl_xor(s, off);
            q += __shfl_xor(q, off);
        }
        float mu = s * (1.f / 288.f);
        float rstd = rsqrtf(q * (1.f / 288.f) - mu * mu + EPSLN);

        unsigned short* xp = xln + (size_t)p * CMID;
        ushort4 o;
        o.x = f2bf((agg[0] - mu) * rstd * ngr[0] + nbr[0]);
        o.y = f2bf((agg[1] - mu) * rstd * ngr[1] + nbr[1]);
        o.z = f2bf((agg[2] - mu) * rstd * ngr[2] + nbr[2]);
        o.w = f2bf((agg[3] - mu) * rstd * ngr[3] + nbr[3]);
        *(ushort4*)(xp + c0) = o;
        if (lane < 32)
            xp[256 + lane] = f2bf((pv - mu) * rstd * ng2 + nb2);
    }
}

// ---------------------------------------------------------------------------
// Conversion kernels
// ---------------------------------------------------------------------------
__global__ __launch_bounds__(256) void transpose_bf16_kernel(
    const float* __restrict__ src, unsigned short* __restrict__ dst, int K, int N)
{
    __shared__ float tile[32][33];
    const int k0 = blockIdx.y * 32, n0 = blockIdx.x * 32;
    const int tx = threadIdx.x & 31, ty = threadIdx.x >> 5;
    #pragma unroll
    for (int i = ty; i < 32; i += 8)
        tile[i][tx] = src[(size_t)(k0 + i) * N + n0 + tx];
    __syncthreads();
    #pragma unroll
    for (int i = ty; i < 32; i += 8)
        dst[(size_t)(n0 + i) * K + k0 + tx] = f2bf(tile[tx][i]);
}

__global__ __launch_bounds__(256) void feats_bf16_kernel(
    const float* __restrict__ src, unsigned short* __restrict__ dst)
{
    int i = (blockIdx.x * 256 + threadIdx.x) * 4;
    float4 v = *(const float4*)(src + i);
    ushort4 o;
    o.x = f2bf(v.x); o.y = f2bf(v.y); o.z = f2bf(v.z); o.w = f2bf(v.w);
    *(ushort4*)(dst + i) = o;
}

// ---------------------------------------------------------------------------
// GEMM 1: h1 = leaky(xln @ l1_w + l1_b), bf16 MFMA, 128x128, BK=32
// ---------------------------------------------------------------------------
__global__ __launch_bounds__(256) void gemm1_mfma(
    const unsigned short* __restrict__ A,
    const unsigned short* __restrict__ BT,
    const float* __restrict__ bias,
    unsigned short* __restrict__ C)
{
    __shared__ unsigned short As[128 * 32];
    __shared__ unsigned short Bs[128 * 32];
    const int t = threadIdx.x;
    const int lane = t & 63, wave = t >> 6;
    const int wm = wave >> 1, wn = wave & 1;
    const int m0 = blockIdx.y * 128, n0 = blockIdx.x * 128;
    const int l15 = lane & 15, j0 = (lane >> 4) << 3;

    f32x4 zero = {0.f, 0.f, 0.f, 0.f};
    f32x4 acc[4][4];
    #pragma unroll
    for (int i = 0; i < 4; ++i)
        #pragma unroll
        for (int j = 0; j < 4; ++j) acc[i][j] = zero;

    for (int kt = 0; kt < CMID; kt += 32) {
        stage_tile(A,  CMID, m0, kt, As, wave, lane);
        stage_tile(BT, CMID, n0, kt, Bs, wave, lane);
        __syncthreads();
        short8 af[4], bf[4];
        #pragma unroll
        for (int i = 0; i < 4; ++i) {
            int ar = wm * 64 + i * 16 + l15;
            af[i] = *(const short8*)&As[ar * 32 + (j0 ^ ((ar & 3) << 3))];
            int br = wn * 64 + i * 16 + l15;
            bf[i] = *(const short8*)&Bs[br * 32 + (j0 ^ ((br & 3) << 3))];
        }
        #pragma unroll
        for (int i = 0; i < 4; ++i)
            #pragma unroll
            for (int j = 0; j < 4; ++j)
                acc[i][j] = __builtin_amdgcn_mfma_f32_16x16x32_bf16(af[i], bf[j], acc[i][j], 0, 0, 0);
        __syncthreads();
    }

    const int q = lane >> 4;
    #pragma unroll
    for (int j = 0; j < 4; ++j) {
        int ncol = n0 + wn * 64 + j * 16 + l15;
        float bv = bias[ncol];
        #pragma unroll
        for (int i = 0; i < 4; ++i) {
            int mbase = m0 + wm * 64 + i * 16 + q * 4;
            #pragma unroll
            for (int r = 0; r < 4; ++r)
                C[(size_t)(mbase + r) * L1OUT + ncol] = f2bf(leaky(acc[i][j][r] + bv));
        }
    }
}

// ---------------------------------------------------------------------------
// GEMM 2: out = leaky(h1 @ l2_w + feats @ sc_w + b2 + bsc), dual-K bf16 MFMA
// ---------------------------------------------------------------------------
__global__ __launch_bounds__(256) void gemm2_mfma(
    const unsigned short* __restrict__ H,
    const unsigned short* __restrict__ W2T,
    const unsigned short* __restrict__ F,
    const unsigned short* __restrict__ WscT,
    const float* __restrict__ b2, const float* __restrict__ bsc,
    float* __restrict__ Out)
{
    __shared__ unsigned short As[128 * 32];
    __shared__ unsigned short Bs[128 * 32];
    const int t = threadIdx.x;
    const int lane = t & 63, wave = t >> 6;
    const int wm = wave >> 1, wn = wave & 1;
    const int m0 = blockIdx.y * 128, n0 = blockIdx.x * 128;
    const int l15 = lane & 15, j0 = (lane >> 4) << 3;

    f32x4 zero = {0.f, 0.f, 0.f, 0.f};
    f32x4 acc[4][4];
    #pragma unroll
    for (int i = 0; i < 4; ++i)
        #pragma unroll
        for (int j = 0; j < 4; ++j) acc[i][j] = zero;

    for (int kt = 0; kt < L1OUT; kt += 32) {
        stage_tile(H,   L1OUT, m0, kt, As, wave, lane);
        stage_tile(W2T, L1OUT, n0, kt, Bs, wave, lane);
        __syncthreads();
        short8 af[4], bf[4];
        #pragma unroll
        for (int i = 0; i < 4; ++i) {
            int ar = wm * 64 + i * 16 + l15;
            af[i] = *(const short8*)&As[ar * 32 + (j0 ^ ((ar & 3) << 3))];
            int br = wn * 64 + i * 16 + l15;
            bf[i] = *(const short8*)&Bs[br * 32 + (j0 ^ ((br & 3) << 3))];
        }
        #pragma unroll
        for (int i = 0; i < 4; ++i)
            #pragma unroll
            for (int j = 0; j < 4; ++j)
                acc[i][j] = __builtin_amdgcn_mfma_f32_16x16x32_bf16(af[i], bf[j], acc[i][j], 0, 0, 0);
        __syncthreads();
    }
    for (int kt = 0; kt < CINC; kt += 32) {
        stage_tile(F,    CINC, m0, kt, As, wave, lane);
        stage_tile(WscT, CINC, n0, kt, Bs, wave, lane);
        __syncthreads();
        short8 af[4], bf[4];
        #pragma unroll
        for (int i = 0; i < 4; ++i) {
            int ar = wm * 64 + i * 16 + l15;
            af[i] = *(const short8*)&As[ar * 32 + (j0 ^ ((ar & 3) << 3))];
            int br = wn * 64 + i * 16 + l15;
            bf[i] = *(const short8*)&Bs[br * 32 + (j0 ^ ((br & 3) << 3))];
        }
        #pragma unroll
        for (int i = 0; i < 4; ++i)
            #pragma unroll
            for (int j = 0; j < 4; ++j)
                acc[i][j] = __builtin_amdgcn_mfma_f32_16x16x32_bf16(af[i], bf[j], acc[i][j], 0, 0, 0);
        __syncthreads();
    }

    const int q = lane >> 4;
    #pragma unroll
    for (int j = 0; j < 4; ++j) {
        int ncol = n0 + wn * 64 + j * 16 + l15;
        float bv = b2[ncol] + bsc[ncol];
        #pragma unroll
        for (int i = 0; i < 4; ++i) {
            int mbase = m0 + wm * 64 + i * 16 + q * 4;
            #pragma unroll
            for (int r = 0; r < 4; ++r)
                Out[(size_t)(mbase + r) * COUTC + ncol] = leaky(acc[i][j][r] + bv);
        }
    }
}

extern "C" void kernel_launch(void* const* d_in, const int* in_sizes, int n_in,
                              void* d_out, int out_size, void* d_ws, size_t ws_size,
                              hipStream_t stream)
{
    const float* xyz    = (const float*)d_in[0];
    const float* feats  = (const float*)d_in[1];
    const int*   nei    = (const int*)d_in[2];
    const float* pe_w1  = (const float*)d_in[3];
    const float* pe_b1  = (const float*)d_in[4];
    const float* pe_g1  = (const float*)d_in[5];
    const float* pe_be1 = (const float*)d_in[6];
    const float* pe_w2  = (const float*)d_in[7];
    const float* pe_b2  = (const float*)d_in[8];
    const float* pe_g2  = (const float*)d_in[9];
    const float* pe_be2 = (const float*)d_in[10];
    const float* wn_w1  = (const float*)d_in[11];
    const float* wn_b1  = (const float*)d_in[12];
    const float* wn_g1  = (const float*)d_in[13];
    const float* wn_be1 = (const float*)d_in[14];
    const float* wn_w2  = (const float*)d_in[15];
    const float* wn_b2  = (const float*)d_in[16];
    const float* wn_g2  = (const float*)d_in[17];
    const float* wn_be2 = (const float*)d_in[18];
    const float* wn_w3  = (const float*)d_in[19];
    const float* wn_b3  = (const float*)d_in[20];
    const float* wn_g3  = (const float*)d_in[21];
    const float* wn_be3 = (const float*)d_in[22];
    const float* nm_g   = (const float*)d_in[23];
    const float* nm_b   = (const float*)d_in[24];
    const float* l1_w   = (const float*)d_in[25];
    const float* l1_b   = (const float*)d_in[26];
    const float* l2_w   = (const float*)d_in[27];
    const float* l2_b   = (const float*)d_in[28];
    const float* sc_w   = (const float*)d_in[29];
    const float* sc_b   = (const float*)d_in[30];

    char* ws = (char*)d_ws;
    unsigned short* xln    = (unsigned short*)(ws);               // 18,874,368
    unsigned short* featsb = (unsigned short*)(ws + 18874368);    // 16,777,216
    unsigned short* l1_wT  = (unsigned short*)(ws + 35651584);    //    589,824
    unsigned short* l2_wT  = (unsigned short*)(ws + 36241408);    //  1,048,576
    unsigned short* sc_wT  = (unsigned short*)(ws + 37289984);    //    262,144
    float*          st     = (float*)(ws + 37552128);             //      4,096
    unsigned short* h1     = (unsigned short*)(ws + 37556224);    // 67,108,864

    wn3_stats_kernel<<<1, 256, 0, stream>>>(wn_w3, wn_b3, st);
    transpose_bf16_kernel<<<dim3(L1OUT / 32, CMID / 32), 256, 0, stream>>>(l1_w, l1_wT, CMID, L1OUT);
    transpose_bf16_kernel<<<dim3(COUTC / 32, L1OUT / 32), 256, 0, stream>>>(l2_w, l2_wT, L1OUT, COUTC);
    transpose_bf16_kernel<<<dim3(COUTC / 32, CINC / 32), 256, 0, stream>>>(sc_w, sc_wT, CINC, COUTC);
    feats_bf16_kernel<<<(NPTS * CINC / 4) / 256, 256, 0, stream>>>(feats, featsb);

    edge_fused_kernel<<<NPTS / PBLK, 256, 0, stream>>>(
        xyz, featsb, nei,
        pe_w1, pe_b1, pe_g1, pe_be1, pe_w2, pe_b2, pe_g2, pe_be2,
        wn_w1, wn_b1, wn_g1, wn_be1, wn_w2, wn_b2, wn_g2, wn_be2,
        st, wn_w3, wn_b3, wn_g3, wn_be3, nm_g, nm_b, xln);

    gemm1_mfma<<<dim3(L1OUT / 128, NPTS / 128), 256, 0, stream>>>(xln, l1_wT, l1_b, h1);

    gemm2_mfma<<<dim3(COUTC / 128, NPTS / 128), 256, 0, stream>>>(
        h1, l2_wT, featsb, sc_wT, l2_b, sc_b, (float*)d_out);
}

// Round 7
// 425.574 us; speedup vs baseline: 3.1439x; 1.2887x over previous
//
#include <hip/hip_runtime.h>

#define NPTS  32768
#define KNB   16
#define CINC  256
#define PEC   32
#define HWN   16
#define CMID  288
#define L1OUT 1024
#define COUTC 512
#define EPSLN 1e-5f
#define PBLK  16

typedef __attribute__((ext_vector_type(8))) short short8;
typedef __attribute__((ext_vector_type(4))) float f32x4;

__device__ __forceinline__ float leaky(float x) { return x > 0.f ? x : 0.1f * x; }

__device__ __forceinline__ float bf2f(unsigned short u) {
    union { unsigned int i; float f; } x; x.i = ((unsigned int)u) << 16; return x.f;
}
__device__ __forceinline__ unsigned short f2bf(float f) {
    unsigned int x = __float_as_uint(f);
    x = (x + 0x7fffu + ((x >> 16) & 1u)) >> 16;
    return (unsigned short)x;
}

// async global->LDS, 16B per lane, dest = wave-uniform base + lane*16
__device__ __forceinline__ void gld_lds16(const unsigned short* g, unsigned short* l) {
    __builtin_amdgcn_global_load_lds(
        (const __attribute__((address_space(1))) unsigned int*)g,
        (__attribute__((address_space(3))) unsigned int*)l,
        16, 0, 0);
}

__device__ __forceinline__ void stage_tile(const unsigned short* __restrict__ g,
                                           size_t ld, int row0, int k0,
                                           unsigned short* lds, int wave, int lane)
{
    #pragma unroll
    for (int r = 0; r < 2; ++r) {
        int e   = r * 2048 + wave * 512 + lane * 8;
        int row = e >> 5;
        int kp  = e & 31;
        int kl  = kp ^ ((row & 3) << 3);
        const unsigned short* src = g + (size_t)(row0 + row) * ld + (k0 + kl);
        gld_lds16(src, lds + r * 2048 + wave * 512);
    }
}

// ---------------------------------------------------------------------------
// Stats kernel (parallel, 66 blocks): folded LN(256) stats of wn3.
// st layout: G @0 (256), wm3 @256 (16), gb @272 (16), bm3 @288, bsq @289.
// blocks 0..63: wave w computes G[pair], pair = b*4+w.
// block 64: wave w computes wm3/gb for h = w*4+i, i=0..3.
// block 65: wave 0 computes bm3/bsq.
// ---------------------------------------------------------------------------
__global__ __launch_bounds__(256) void wn3_stats_kernel(
    const float* __restrict__ W3, const float* __restrict__ b3, float* __restrict__ st)
{
    const int b = blockIdx.x;
    const int t = threadIdx.x;
    const int lane = t & 63, wave = t >> 6;
    const int c0 = lane * 4;

    if (b < 64) {
        int pair = b * 4 + wave;
        int h = pair >> 4, hp = pair & 15;
        f32x4 a  = *(const f32x4*)(W3 + h * CINC + c0);
        f32x4 bb = *(const f32x4*)(W3 + hp * CINC + c0);
        float g = a[0] * bb[0] + a[1] * bb[1] + a[2] * bb[2] + a[3] * bb[3];
        #pragma unroll
        for (int off = 1; off < 64; off <<= 1) g += __shfl_xor(g, off);
        if (lane == 0) st[pair] = g * (1.f / CINC);
    } else if (b == 64) {
        #pragma unroll
        for (int i = 0; i < 4; ++i) {
            int h = wave * 4 + i;
            f32x4 w  = *(const f32x4*)(W3 + h * CINC + c0);
            f32x4 bb = *(const f32x4*)(b3 + c0);
            float s  = w[0] + w[1] + w[2] + w[3];
            float sb = w[0] * bb[0] + w[1] * bb[1] + w[2] * bb[2] + w[3] * bb[3];
            #pragma unroll
            for (int off = 1; off < 64; off <<= 1) { s += __shfl_xor(s, off); sb += __shfl_xor(sb, off); }
            if (lane == 0) { st[256 + h] = s * (1.f / CINC); st[272 + h] = sb * (1.f / CINC); }
        }
    } else if (wave == 0) {
        f32x4 bb = *(const f32x4*)(b3 + c0);
        float s = bb[0] + bb[1] + bb[2] + bb[3];
        float q = bb[0] * bb[0] + bb[1] * bb[1] + bb[2] * bb[2] + bb[3] * bb[3];
        #pragma unroll
        for (int off = 1; off < 64; off <<= 1) { s += __shfl_xor(s, off); q += __shfl_xor(q, off); }
        if (lane == 0) { st[288] = s * (1.f / CINC); st[289] = q * (1.f / CINC); }
    }
}

// packed small-weight LDS offsets (floats)
#define PEW1  0
#define PEB1  96
#define PEG1  128
#define PEBE1 160
#define PEW2  192
#define PEB2  1216
#define PEG2  1248
#define PEBE2 1280
#define WNW1  1312
#define WNB1  1360
#define WNG1  1376
#define WNBE1 1392
#define WNW2  1408
#define WNB2  1664
#define WNG2  1680
#define WNBE2 1696
#define STO   1712
// total 2002 -> round to 2008

// ---------------------------------------------------------------------------
// Fused edge kernel, occupancy-tuned (R7):
//  - __launch_bounds__(256,3): LDS (44KB) caps at 3 blocks/CU = 37.5% occ,
//    so target ~170 VGPRs (2048/12 waves), not 128.
//  - Phase A: WN branch first (small regs), then PE; j-loops unroll 2 to
//    limit in-flight ds_read results.
//  - Phase B: k-loop in 2 chunks of 8 -> raw[8][4] (32 regs vs 64).
// ---------------------------------------------------------------------------
__global__ __launch_bounds__(256, 3) void edge_fused_kernel(
    const float* __restrict__ xyz, const unsigned short* __restrict__ featsb,
    const int* __restrict__ nei,
    const float* __restrict__ pe_w1, const float* __restrict__ pe_b1,
    const float* __restrict__ pe_g1, const float* __restrict__ pe_be1,
    const float* __restrict__ pe_w2, const float* __restrict__ pe_b2,
    const float* __restrict__ pe_g2, const float* __restrict__ pe_be2,
    const float* __restrict__ wn_w1, const float* __restrict__ wn_b1,
    const float* __restrict__ wn_g1, const float* __restrict__ wn_be1,
    const float* __restrict__ wn_w2, const float* __restrict__ wn_b2,
    const float* __restrict__ wn_g2, const float* __restrict__ wn_be2,
    const float* __restrict__ st,
    const float* __restrict__ wn_w3, const float* __restrict__ wn_b3,
    const float* __restrict__ wn_g3, const float* __restrict__ wn_be3,
    const float* __restrict__ nm_g, const float* __restrict__ nm_b,
    unsigned short* __restrict__ xln)
{
    __shared__ __align__(16) float Ws[2008];
    __shared__ __align__(16) float W3s[16 * 256];
    __shared__ __align__(16) float w2s[PBLK * 256];   // [lp][hh][k]
    __shared__ float rms[PBLK * 16], mus[PBLK * 16], pes[PBLK * 32];

    const int t = threadIdx.x;

    // ---- stage weights + stats into LDS (audited: every region staged) ----
    if (t < 96) Ws[PEW1 + t] = pe_w1[t];
    if (t < 32) {
        Ws[PEB1 + t] = pe_b1[t];  Ws[PEG1 + t] = pe_g1[t];  Ws[PEBE1 + t] = pe_be1[t];
        Ws[PEB2 + t] = pe_b2[t];  Ws[PEG2 + t] = pe_g2[t];  Ws[PEBE2 + t] = pe_be2[t];
    }
    for (int i = t; i < 1024; i += 256) Ws[PEW2 + i] = pe_w2[i];
    if (t < 48) Ws[WNW1 + t] = wn_w1[t];
    Ws[WNW2 + t] = wn_w2[t];                      // BUGFIX R5: must stage wn_w2
    if (t < 16) {
        Ws[WNB1 + t] = wn_b1[t];  Ws[WNG1 + t] = wn_g1[t];  Ws[WNBE1 + t] = wn_be1[t];
        Ws[WNB2 + t] = wn_b2[t];  Ws[WNG2 + t] = wn_g2[t];  Ws[WNBE2 + t] = wn_be2[t];
    }
    for (int i = t; i < 290; i += 256) Ws[STO + i] = st[i];   // BUGFIX R4: stride
    for (int i = t; i < 4096; i += 256) W3s[i] = wn_w3[i];
    __syncthreads();

    // ======================= Phase A: per-edge MLPs =======================
    {
        const int lp = t >> 4, kk = t & 15;
        const int m = blockIdx.x * PBLK + lp;
        const int n = nei[m * KNB + kk];
        const float lx = xyz[n * 3 + 0] - xyz[m * 3 + 0];
        const float ly = xyz[n * 3 + 1] - xyz[m * 3 + 1];
        const float lz = xyz[n * 3 + 2] - xyz[m * 3 + 2];

        // ---- WN branch first (small register arrays) ----
        float w1[16];
        float s = 0.f, q = 0.f;
        #pragma unroll
        for (int c4 = 0; c4 < 4; ++c4) {
            f32x4 wa = *(const f32x4*)&Ws[WNW1 + c4 * 4];
            f32x4 wb = *(const f32x4*)&Ws[WNW1 + 16 + c4 * 4];
            f32x4 wc = *(const f32x4*)&Ws[WNW1 + 32 + c4 * 4];
            f32x4 bb = *(const f32x4*)&Ws[WNB1 + c4 * 4];
            #pragma unroll
            for (int j = 0; j < 4; ++j) {
                float v = bb[j] + lx * wa[j] + ly * wb[j] + lz * wc[j];
                w1[c4 * 4 + j] = v; s += v; q += v * v;
            }
        }
        float mu = s * (1.f / 16.f);
        float rstd = rsqrtf(q * (1.f / 16.f) - mu * mu + EPSLN);
        #pragma unroll
        for (int c4 = 0; c4 < 4; ++c4) {
            f32x4 g = *(const f32x4*)&Ws[WNG1 + c4 * 4];
            f32x4 be = *(const f32x4*)&Ws[WNBE1 + c4 * 4];
            #pragma unroll
            for (int j = 0; j < 4; ++j) {
                int c = c4 * 4 + j;
                w1[c] = leaky((w1[c] - mu) * rstd * g[j] + be[j]);
            }
        }

        float w2[16];
        #pragma unroll
        for (int c4 = 0; c4 < 4; ++c4) {
            f32x4 bb = *(const f32x4*)&Ws[WNB2 + c4 * 4];
            w2[c4 * 4 + 0] = bb[0]; w2[c4 * 4 + 1] = bb[1];
            w2[c4 * 4 + 2] = bb[2]; w2[c4 * 4 + 3] = bb[3];
        }
        #pragma unroll 2
        for (int j = 0; j < 16; ++j) {
            float wj = w1[j];
            #pragma unroll
            for (int c4 = 0; c4 < 4; ++c4) {
                f32x4 w = *(const f32x4*)&Ws[WNW2 + j * 16 + c4 * 4];
                w2[c4 * 4 + 0] += wj * w[0]; w2[c4 * 4 + 1] += wj * w[1];
                w2[c4 * 4 + 2] += wj * w[2]; w2[c4 * 4 + 3] += wj * w[3];
            }
        }
        s = 0.f; q = 0.f;
        #pragma unroll
        for (int c = 0; c < 16; ++c) { s += w2[c]; q += w2[c] * w2[c]; }
        mu = s * (1.f / 16.f);
        rstd = rsqrtf(q * (1.f / 16.f) - mu * mu + EPSLN);
        #pragma unroll
        for (int c4 = 0; c4 < 4; ++c4) {
            f32x4 g = *(const f32x4*)&Ws[WNG2 + c4 * 4];
            f32x4 be = *(const f32x4*)&Ws[WNBE2 + c4 * 4];
            #pragma unroll
            for (int j = 0; j < 4; ++j) {
                int c = c4 * 4 + j;
                w2[c] = leaky((w2[c] - mu) * rstd * g[j] + be[j]);
            }
        }

        // folded LN(256) stats
        float mu3 = Ws[STO + 288];
        #pragma unroll
        for (int h4 = 0; h4 < 4; ++h4) {
            f32x4 wm = *(const f32x4*)&Ws[STO + 256 + h4 * 4];
            mu3 += w2[h4 * 4 + 0] * wm[0] + w2[h4 * 4 + 1] * wm[1]
                 + w2[h4 * 4 + 2] * wm[2] + w2[h4 * 4 + 3] * wm[3];
        }
        float esq = Ws[STO + 289];
        #pragma unroll 4
        for (int hh = 0; hh < 16; ++hh) {
            float acc = 2.f * Ws[STO + 272 + hh];
            #pragma unroll
            for (int h4 = 0; h4 < 4; ++h4) {
                f32x4 g = *(const f32x4*)&Ws[STO + hh * 16 + h4 * 4];
                acc += g[0] * w2[h4 * 4 + 0] + g[1] * w2[h4 * 4 + 1]
                     + g[2] * w2[h4 * 4 + 2] + g[3] * w2[h4 * 4 + 3];
            }
            esq += w2[hh] * acc;
        }
        float r3 = rsqrtf(esq - mu3 * mu3 + EPSLN);

        #pragma unroll
        for (int hh = 0; hh < 16; ++hh) w2s[lp * 256 + hh * 16 + kk] = w2[hh];
        rms[lp * 16 + kk] = r3;
        mus[lp * 16 + kk] = mu3;

        // ---- PE branch (w1/w2 dead now) ----
        float h[32];
        s = 0.f; q = 0.f;
        #pragma unroll
        for (int c4 = 0; c4 < 8; ++c4) {
            f32x4 wa = *(const f32x4*)&Ws[PEW1 + c4 * 4];
            f32x4 wb = *(const f32x4*)&Ws[PEW1 + 32 + c4 * 4];
            f32x4 wc = *(const f32x4*)&Ws[PEW1 + 64 + c4 * 4];
            f32x4 bb = *(const f32x4*)&Ws[PEB1 + c4 * 4];
            #pragma unroll
            for (int j = 0; j < 4; ++j) {
                float v = bb[j] + lx * wa[j] + ly * wb[j] + lz * wc[j];
                h[c4 * 4 + j] = v; s += v; q += v * v;
            }
        }
        mu = s * (1.f / 32.f);
        rstd = rsqrtf(q * (1.f / 32.f) - mu * mu + EPSLN);
        #pragma unroll
        for (int c4 = 0; c4 < 8; ++c4) {
            f32x4 g = *(const f32x4*)&Ws[PEG1 + c4 * 4];
            f32x4 be = *(const f32x4*)&Ws[PEBE1 + c4 * 4];
            #pragma unroll
            for (int j = 0; j < 4; ++j) {
                int c = c4 * 4 + j;
                h[c] = leaky((h[c] - mu) * rstd * g[j] + be[j]);
            }
        }

        float f[32];
        #pragma unroll
        for (int c4 = 0; c4 < 8; ++c4) {
            f32x4 bb = *(const f32x4*)&Ws[PEB2 + c4 * 4];
            f[c4 * 4 + 0] = bb[0]; f[c4 * 4 + 1] = bb[1];
            f[c4 * 4 + 2] = bb[2]; f[c4 * 4 + 3] = bb[3];
        }
        #pragma unroll 2
        for (int j = 0; j < 32; ++j) {
            float hj = h[j];
            #pragma unroll
            for (int c4 = 0; c4 < 8; ++c4) {
                f32x4 w = *(const f32x4*)&Ws[PEW2 + j * 32 + c4 * 4];
                f[c4 * 4 + 0] += hj * w[0]; f[c4 * 4 + 1] += hj * w[1];
                f[c4 * 4 + 2] += hj * w[2]; f[c4 * 4 + 3] += hj * w[3];
            }
        }
        s = 0.f; q = 0.f;
        #pragma unroll
        for (int c = 0; c < 32; ++c) { s += f[c]; q += f[c] * f[c]; }
        mu = s * (1.f / 32.f);
        rstd = rsqrtf(q * (1.f / 32.f) - mu * mu + EPSLN);
        #pragma unroll
        for (int c4 = 0; c4 < 8; ++c4) {
            f32x4 g = *(const f32x4*)&Ws[PEG2 + c4 * 4];
            f32x4 be = *(const f32x4*)&Ws[PEBE2 + c4 * 4];
            #pragma unroll
            for (int j = 0; j < 4; ++j) {
                int c = c4 * 4 + j;
                float v = (f[c] - mu) * rstd * g[j] + be[j];
                v += __shfl_xor(v, 1);
                v += __shfl_xor(v, 2);
                v += __shfl_xor(v, 4);
                v += __shfl_xor(v, 8);
                if (kk == 0) pes[lp * 32 + c] = v;
            }
        }
    }
    __syncthreads();

    // ======================= Phase B: per-point aggregation ================
    const int lane = t & 63, wave = t >> 6;
    const int c0 = lane * 4;
    const f32x4 b3r  = *(const f32x4*)(wn_b3 + c0);
    const f32x4 g3r  = *(const f32x4*)(wn_g3 + c0);
    const f32x4 be3r = *(const f32x4*)(wn_be3 + c0);

    for (int pp = 0; pp < 4; ++pp) {
        const int lp = wave * 4 + pp;
        const int p  = blockIdx.x * PBLK + lp;
        const int* np = nei + p * KNB;

        float agg[4] = {0.f, 0.f, 0.f, 0.f};

        #pragma unroll
        for (int kc = 0; kc < 2; ++kc) {      // k in 2 chunks of 8 -> raw regs halved
            float raw[8][4];
            #pragma unroll
            for (int k = 0; k < 8; ++k)
                #pragma unroll
                for (int j = 0; j < 4; ++j) raw[k][j] = 0.f;

            #pragma unroll 4
            for (int hh = 0; hh < 16; ++hh) {
                f32x4 w3r = *(const f32x4*)&W3s[hh * 256 + c0];
                f32x4 u0 = *(const f32x4*)&w2s[lp * 256 + hh * 16 + kc * 8];
                f32x4 u1 = *(const f32x4*)&w2s[lp * 256 + hh * 16 + kc * 8 + 4];
                #pragma unroll
                for (int k = 0; k < 4; ++k) {
                    raw[k][0] += u0[k] * w3r[0];
                    raw[k][1] += u0[k] * w3r[1];
                    raw[k][2] += u0[k] * w3r[2];
                    raw[k][3] += u0[k] * w3r[3];
                }
                #pragma unroll
                for (int k = 0; k < 4; ++k) {
                    raw[4 + k][0] += u1[k] * w3r[0];
                    raw[4 + k][1] += u1[k] * w3r[1];
                    raw[4 + k][2] += u1[k] * w3r[2];
                    raw[4 + k][3] += u1[k] * w3r[3];
                }
            }

            #pragma unroll
            for (int k8 = 0; k8 < 8; ++k8) {
                int k = kc * 8 + k8;
                int nk = np[k];
                float rk  = rms[lp * 16 + k];
                float muk = mus[lp * 16 + k];
                ushort4 fu = *(const ushort4*)(featsb + (size_t)nk * CINC + c0);
                float w3x = (raw[k8][0] + b3r[0] - muk) * rk * g3r[0] + be3r[0];
                float w3y = (raw[k8][1] + b3r[1] - muk) * rk * g3r[1] + be3r[1];
                float w3z = (raw[k8][2] + b3r[2] - muk) * rk * g3r[2] + be3r[2];
                float w3w = (raw[k8][3] + b3r[3] - muk) * rk * g3r[3] + be3r[3];
                agg[0] += bf2f(fu.x) * w3x;
                agg[1] += bf2f(fu.y) * w3y;
                agg[2] += bf2f(fu.z) * w3z;
                agg[3] += bf2f(fu.w) * w3w;
            }
        }

        float pv = (lane < 32) ? pes[lp * 32 + lane] : 0.f;

        float s = agg[0] + agg[1] + agg[2] + agg[3];
        float q = agg[0] * agg[0] + agg[1] * agg[1] + agg[2] * agg[2] + agg[3] * agg[3];
        if (lane < 32) { s += pv; q += pv * pv; }
        #pragma unroll
        for (int off = 1; off < 64; off <<= 1) {
            s += __shfl_xor(s, off);
            q += __shfl_xor(q, off);
        }
        float mu = s * (1.f / 288.f);
        float rstd = rsqrtf(q * (1.f / 288.f) - mu * mu + EPSLN);

        // epilogue constants loaded at use to shorten live ranges
        f32x4 ngr = *(const f32x4*)(nm_g + c0);
        f32x4 nbr = *(const f32x4*)(nm_b + c0);
        unsigned short* xp = xln + (size_t)p * CMID;
        ushort4 o;
        o.x = f2bf((agg[0] - mu) * rstd * ngr[0] + nbr[0]);
        o.y = f2bf((agg[1] - mu) * rstd * ngr[1] + nbr[1]);
        o.z = f2bf((agg[2] - mu) * rstd * ngr[2] + nbr[2]);
        o.w = f2bf((agg[3] - mu) * rstd * ngr[3] + nbr[3]);
        *(ushort4*)(xp + c0) = o;
        if (lane < 32)
            xp[256 + lane] = f2bf((pv - mu) * rstd * nm_g[256 + lane] + nm_b[256 + lane]);
    }
}

// ---------------------------------------------------------------------------
// Conversion kernels
// ---------------------------------------------------------------------------
__global__ __launch_bounds__(256) void transpose_bf16_kernel(
    const float* __restrict__ src, unsigned short* __restrict__ dst, int K, int N)
{
    __shared__ float tile[32][33];
    const int k0 = blockIdx.y * 32, n0 = blockIdx.x * 32;
    const int tx = threadIdx.x & 31, ty = threadIdx.x >> 5;
    #pragma unroll
    for (int i = ty; i < 32; i += 8)
        tile[i][tx] = src[(size_t)(k0 + i) * N + n0 + tx];
    __syncthreads();
    #pragma unroll
    for (int i = ty; i < 32; i += 8)
        dst[(size_t)(n0 + i) * K + k0 + tx] = f2bf(tile[tx][i]);
}

__global__ __launch_bounds__(256) void feats_bf16_kernel(
    const float* __restrict__ src, unsigned short* __restrict__ dst)
{
    int i = (blockIdx.x * 256 + threadIdx.x) * 4;
    float4 v = *(const float4*)(src + i);
    ushort4 o;
    o.x = f2bf(v.x); o.y = f2bf(v.y); o.z = f2bf(v.z); o.w = f2bf(v.w);
    *(ushort4*)(dst + i) = o;
}

// ---------------------------------------------------------------------------
// GEMM 1: h1 = leaky(xln @ l1_w + l1_b), bf16 MFMA, 128x128, BK=32
// ---------------------------------------------------------------------------
__global__ __launch_bounds__(256) void gemm1_mfma(
    const unsigned short* __restrict__ A,
    const unsigned short* __restrict__ BT,
    const float* __restrict__ bias,
    unsigned short* __restrict__ C)
{
    __shared__ unsigned short As[128 * 32];
    __shared__ unsigned short Bs[128 * 32];
    const int t = threadIdx.x;
    const int lane = t & 63, wave = t >> 6;
    const int wm = wave >> 1, wn = wave & 1;
    const int m0 = blockIdx.y * 128, n0 = blockIdx.x * 128;
    const int l15 = lane & 15, j0 = (lane >> 4) << 3;

    f32x4 zero = {0.f, 0.f, 0.f, 0.f};
    f32x4 acc[4][4];
    #pragma unroll
    for (int i = 0; i < 4; ++i)
        #pragma unroll
        for (int j = 0; j < 4; ++j) acc[i][j] = zero;

    for (int kt = 0; kt < CMID; kt += 32) {
        stage_tile(A,  CMID, m0, kt, As, wave, lane);
        stage_tile(BT, CMID, n0, kt, Bs, wave, lane);
        __syncthreads();
        short8 af[4], bf[4];
        #pragma unroll
        for (int i = 0; i < 4; ++i) {
            int ar = wm * 64 + i * 16 + l15;
            af[i] = *(const short8*)&As[ar * 32 + (j0 ^ ((ar & 3) << 3))];
            int br = wn * 64 + i * 16 + l15;
            bf[i] = *(const short8*)&Bs[br * 32 + (j0 ^ ((br & 3) << 3))];
        }
        #pragma unroll
        for (int i = 0; i < 4; ++i)
            #pragma unroll
            for (int j = 0; j < 4; ++j)
                acc[i][j] = __builtin_amdgcn_mfma_f32_16x16x32_bf16(af[i], bf[j], acc[i][j], 0, 0, 0);
        __syncthreads();
    }

    const int q = lane >> 4;
    #pragma unroll
    for (int j = 0; j < 4; ++j) {
        int ncol = n0 + wn * 64 + j * 16 + l15;
        float bv = bias[ncol];
        #pragma unroll
        for (int i = 0; i < 4; ++i) {
            int mbase = m0 + wm * 64 + i * 16 + q * 4;
            #pragma unroll
            for (int r = 0; r < 4; ++r)
                C[(size_t)(mbase + r) * L1OUT + ncol] = f2bf(leaky(acc[i][j][r] + bv));
        }
    }
}

// ---------------------------------------------------------------------------
// GEMM 2: out = leaky(h1 @ l2_w + feats @ sc_w + b2 + bsc), dual-K bf16 MFMA
// ---------------------------------------------------------------------------
__global__ __launch_bounds__(256) void gemm2_mfma(
    const unsigned short* __restrict__ H,
    const unsigned short* __restrict__ W2T,
    const unsigned short* __restrict__ F,
    const unsigned short* __restrict__ WscT,
    const float* __restrict__ b2, const float* __restrict__ bsc,
    float* __restrict__ Out)
{
    __shared__ unsigned short As[128 * 32];
    __shared__ unsigned short Bs[128 * 32];
    const int t = threadIdx.x;
    const int lane = t & 63, wave = t >> 6;
    const int wm = wave >> 1, wn = wave & 1;
    const int m0 = blockIdx.y * 128, n0 = blockIdx.x * 128;
    const int l15 = lane & 15, j0 = (lane >> 4) << 3;

    f32x4 zero = {0.f, 0.f, 0.f, 0.f};
    f32x4 acc[4][4];
    #pragma unroll
    for (int i = 0; i < 4; ++i)
        #pragma unroll
        for (int j = 0; j < 4; ++j) acc[i][j] = zero;

    for (int kt = 0; kt < L1OUT; kt += 32) {
        stage_tile(H,   L1OUT, m0, kt, As, wave, lane);
        stage_tile(W2T, L1OUT, n0, kt, Bs, wave, lane);
        __syncthreads();
        short8 af[4], bf[4];
        #pragma unroll
        for (int i = 0; i < 4; ++i) {
            int ar = wm * 64 + i * 16 + l15;
            af[i] = *(const short8*)&As[ar * 32 + (j0 ^ ((ar & 3) << 3))];
            int br = wn * 64 + i * 16 + l15;
            bf[i] = *(const short8*)&Bs[br * 32 + (j0 ^ ((br & 3) << 3))];
        }
        #pragma unroll
        for (int i = 0; i < 4; ++i)
            #pragma unroll
            for (int j = 0; j < 4; ++j)
                acc[i][j] = __builtin_amdgcn_mfma_f32_16x16x32_bf16(af[i], bf[j], acc[i][j], 0, 0, 0);
        __syncthreads();
    }
    for (int kt = 0; kt < CINC; kt += 32) {
        stage_tile(F,    CINC, m0, kt, As, wave, lane);
        stage_tile(WscT, CINC, n0, kt, Bs, wave, lane);
        __syncthreads();
        short8 af[4], bf[4];
        #pragma unroll
        for (int i = 0; i < 4; ++i) {
            int ar = wm * 64 + i * 16 + l15;
            af[i] = *(const short8*)&As[ar * 32 + (j0 ^ ((ar & 3) << 3))];
            int br = wn * 64 + i * 16 + l15;
            bf[i] = *(const short8*)&Bs[br * 32 + (j0 ^ ((br & 3) << 3))];
        }
        #pragma unroll
        for (int i = 0; i < 4; ++i)
            #pragma unroll
            for (int j = 0; j < 4; ++j)
                acc[i][j] = __builtin_amdgcn_mfma_f32_16x16x32_bf16(af[i], bf[j], acc[i][j], 0, 0, 0);
        __syncthreads();
    }

    const int q = lane >> 4;
    #pragma unroll
    for (int j = 0; j < 4; ++j) {
        int ncol = n0 + wn * 64 + j * 16 + l15;
        float bv = b2[ncol] + bsc[ncol];
        #pragma unroll
        for (int i = 0; i < 4; ++i) {
            int mbase = m0 + wm * 64 + i * 16 + q * 4;
            #pragma unroll
            for (int r = 0; r < 4; ++r)
                Out[(size_t)(mbase + r) * COUTC + ncol] = leaky(acc[i][j][r] + bv);
        }
    }
}

extern "C" void kernel_launch(void* const* d_in, const int* in_sizes, int n_in,
                              void* d_out, int out_size, void* d_ws, size_t ws_size,
                              hipStream_t stream)
{
    const float* xyz    = (const float*)d_in[0];
    const float* feats  = (const float*)d_in[1];
    const int*   nei    = (const int*)d_in[2];
    const float* pe_w1  = (const float*)d_in[3];
    const float* pe_b1  = (const float*)d_in[4];
    const float* pe_g1  = (const float*)d_in[5];
    const float* pe_be1 = (const float*)d_in[6];
    const float* pe_w2  = (const float*)d_in[7];
    const float* pe_b2  = (const float*)d_in[8];
    const float* pe_g2  = (const float*)d_in[9];
    const float* pe_be2 = (const float*)d_in[10];
    const float* wn_w1  = (const float*)d_in[11];
    const float* wn_b1  = (const float*)d_in[12];
    const float* wn_g1  = (const float*)d_in[13];
    const float* wn_be1 = (const float*)d_in[14];
    const float* wn_w2  = (const float*)d_in[15];
    const float* wn_b2  = (const float*)d_in[16];
    const float* wn_g2  = (const float*)d_in[17];
    const float* wn_be2 = (const float*)d_in[18];
    const float* wn_w3  = (const float*)d_in[19];
    const float* wn_b3  = (const float*)d_in[20];
    const float* wn_g3  = (const float*)d_in[21];
    const float* wn_be3 = (const float*)d_in[22];
    const float* nm_g   = (const float*)d_in[23];
    const float* nm_b   = (const float*)d_in[24];
    const float* l1_w   = (const float*)d_in[25];
    const float* l1_b   = (const float*)d_in[26];
    const float* l2_w   = (const float*)d_in[27];
    const float* l2_b   = (const float*)d_in[28];
    const float* sc_w   = (const float*)d_in[29];
    const float* sc_b   = (const float*)d_in[30];

    char* ws = (char*)d_ws;
    unsigned short* xln    = (unsigned short*)(ws);               // 18,874,368
    unsigned short* featsb = (unsigned short*)(ws + 18874368);    // 16,777,216
    unsigned short* l1_wT  = (unsigned short*)(ws + 35651584);    //    589,824
    unsigned short* l2_wT  = (unsigned short*)(ws + 36241408);    //  1,048,576
    unsigned short* sc_wT  = (unsigned short*)(ws + 37289984);    //    262,144
    float*          st     = (float*)(ws + 37552128);             //      4,096
    unsigned short* h1     = (unsigned short*)(ws + 37556224);    // 67,108,864

    wn3_stats_kernel<<<66, 256, 0, stream>>>(wn_w3, wn_b3, st);
    transpose_bf16_kernel<<<dim3(L1OUT / 32, CMID / 32), 256, 0, stream>>>(l1_w, l1_wT, CMID, L1OUT);
    transpose_bf16_kernel<<<dim3(COUTC / 32, L1OUT / 32), 256, 0, stream>>>(l2_w, l2_wT, L1OUT, COUTC);
    transpose_bf16_kernel<<<dim3(COUTC / 32, CINC / 32), 256, 0, stream>>>(sc_w, sc_wT, CINC, COUTC);
    feats_bf16_kernel<<<(NPTS * CINC / 4) / 256, 256, 0, stream>>>(feats, featsb);

    edge_fused_kernel<<<NPTS / PBLK, 256, 0, stream>>>(
        xyz, featsb, nei,
        pe_w1, pe_b1, pe_g1, pe_be1, pe_w2, pe_b2, pe_g2, pe_be2,
        wn_w1, wn_b1, wn_g1, wn_be1, wn_w2, wn_b2, wn_g2, wn_be2,
        st, wn_w3, wn_b3, wn_g3, wn_be3, nm_g, nm_b, xln);

    gemm1_mfma<<<dim3(L1OUT / 128, NPTS / 128), 256, 0, stream>>>(xln, l1_wT, l1_b, h1);

    gemm2_mfma<<<dim3(COUTC / 128, NPTS / 128), 256, 0, stream>>>(
        h1, l2_wT, featsb, sc_wT, l2_b, sc_b, (float*)d_out);
}